// Round 11
// baseline (468.304 us; speedup 1.0000x reference)
//
#include <hip/hip_runtime.h>

typedef unsigned short u16;
typedef unsigned int u32;
typedef long long i64;
typedef __attribute__((ext_vector_type(8))) short bf16x8;
typedef __attribute__((ext_vector_type(4))) float f32x4;
typedef __attribute__((ext_vector_type(4))) unsigned short u16x4;
typedef __attribute__((ext_vector_type(2))) unsigned short u16x2;

static const int NN = 8000;    // nodes per graph (M == D)
static const int NE = 256000;  // edges per graph
static const int FF = 512;     // feature dim
static const int MP = 8064;    // 63 * 128 padded rows

__device__ __forceinline__ u16 f2bf(float x) {
  union { float f; u32 u; } a; a.f = x;
  u32 r = a.u + 0x7FFF + ((a.u >> 16) & 1);  // RNE
  return (u16)(r >> 16);
}
__device__ __forceinline__ float bf2f(u16 b) {
  union { float f; u32 u; } a; a.u = ((u32)b) << 16;
  return a.f;
}

__device__ __forceinline__ void gload_lds16(const void* g, void* l) {
  __builtin_amdgcn_global_load_lds(
      (const __attribute__((address_space(1))) unsigned int*)g,
      (__attribute__((address_space(3))) unsigned int*)l, 16, 0, 0);
}

// ---------------- arg structs (blockIdx.z = graph where applicable) --------

struct SetupArgs {
  const float* x[2];
  u16* ph[2];
  u16* pl[2];
  float* deg[2];
  int* cnt[2];
};

struct PreArgs {
  const float* data[2];
  const int* ei[2];
  float* wbuf[2];
  float* deg[2];
  int* cnt[2];
  float* dinv[2];
  int* colptr[2];
  int2* edata[2];  // packed (src, norm-bits)
};

struct WTAll {
  const float* W[10];
  u16* Th[10];
  u16* Tl[10];
  int K[10], N[10];
  int toff[11];
};

struct MMArgs {
  const u16* Ah[2]; const u16* Al[2];
  const u16* Bh[2]; const u16* Bl[2];
  const float* bias[2];
  float* C[2];             // fp32 output (when !OUTPLANES)
  u16* Ch[2]; u16* Cl[2];  // plane outputs (when OUTPLANES)
};

struct AggArgs {
  const float* XW[2];
  const int* colptr[2];
  const int2* edata[2];
  const float* dinv[2];
  const float* bias[2];
  u16* Hh[2];
  u16* Hl[2];
};

// ---------------- setup: split input acts + init deg/cnt ----------------

__global__ __launch_bounds__(256) void k_setup(SetupArgs s, int sb, int tot_in, int tot_pad) {
  int z = blockIdx.z;
  int b = blockIdx.x;
  int tid = threadIdx.x;
  if (b < sb) {
    int i = (b * 256 + tid) * 4;
    if (i >= tot_pad) return;
    float4 v = (i < tot_in) ? *(const float4*)&s.x[z][i] : make_float4(0.f, 0.f, 0.f, 0.f);
    u16x4 h, l;
#pragma unroll
    for (int e = 0; e < 4; ++e) {
      float x = (&v.x)[e];
      u16 hh = f2bf(x);
      h[e] = hh;
      l[e] = f2bf(x - bf2f(hh));
    }
    *(u16x4*)&s.ph[z][i] = h;
    *(u16x4*)&s.pl[z][i] = l;
  } else {
    int i = (b - sb) * 256 + tid;
    if (i < NN) { s.deg[z][i] = 1.0f; s.cnt[z][i] = 0; }
  }
}

// ---------------- edge weights + degree ----------------

__global__ __launch_bounds__(256) void k_edge_w(PreArgs p, int E, int n) {
  int z = blockIdx.z;
  int e = blockIdx.x * 256 + threadIdx.x;
  if (e >= E) return;
  const int* ei = p.ei[z];
  int r = ei[e];
  int c = ei[E + e];
  float w = fmaxf(p.data[z][(size_t)r * n + c], 0.0f);
  p.wbuf[z][e] = w;
  atomicAdd(&p.deg[z][c], w);
  atomicAdd(&p.cnt[z][c], 1);
}

// one block per z: dinv + exclusive scan of cnt -> colptr; zero cnt
__global__ __launch_bounds__(256) void k_scan_dinv(PreArgs p, int n) {
  int z = blockIdx.z;
  const int* cnt = p.cnt[z];
  int* colptr = p.colptr[z];
  int* cntz = p.cnt[z];
  __shared__ int part[256];
  int t = threadIdx.x;
  const int CH = 32;
  int base = t * CH;
  for (int i = 0; i < CH; ++i) {
    int idx = base + i;
    if (idx < n) p.dinv[z][idx] = 1.0f / sqrtf(p.deg[z][idx]);
  }
  int local[CH];
  int s = 0;
  for (int i = 0; i < CH; ++i) {
    int idx = base + i;
    int v = (idx < n) ? cnt[idx] : 0;
    local[i] = s;
    s += v;
  }
  part[t] = s;
  __syncthreads();
  for (int o = 1; o < 256; o <<= 1) {
    int v = (t >= o) ? part[t - o] : 0;
    __syncthreads();
    part[t] += v;
    __syncthreads();
  }
  int pre = (t == 0) ? 0 : part[t - 1];
  for (int i = 0; i < CH; ++i) {
    int idx = base + i;
    if (idx < n) { colptr[idx] = pre + local[i]; cntz[idx] = 0; }
  }
  if (t == 255) colptr[n] = part[255];
}

__global__ __launch_bounds__(256) void k_scatter(PreArgs p, int E) {
  int z = blockIdx.z;
  int e = blockIdx.x * 256 + threadIdx.x;
  if (e >= E) return;
  const int* ei = p.ei[z];
  int r = ei[e], c = ei[E + e];
  int pos = p.colptr[z][c] + atomicAdd(&p.cnt[z][c], 1);
  int2 sn;
  sn.x = r;
  sn.y = __float_as_int(p.dinv[z][r] * p.wbuf[z][e] * p.dinv[z][c]);
  p.edata[z][pos] = sn;
}

// ---------------- all weight transposes+splits in one launch ----------------
// W [K][N] -> Th/Tl [N][K] for 10 matrices.

__global__ __launch_bounds__(256) void k_splitW_all(WTAll a) {
  int bid = blockIdx.x;
  int m = 0;
  while (bid >= a.toff[m + 1]) ++m;
  int local = bid - a.toff[m];
  int K = a.K[m], N = a.N[m];
  int ntn = N >> 5;
  int n0 = (local % ntn) * 32, k0 = (local / ntn) * 32;
  const float* W = a.W[m];
  u16* Th = a.Th[m];
  u16* Tl = a.Tl[m];
  __shared__ float tile[32][33];
  int tx = threadIdx.x & 31, ty = threadIdx.x >> 5;
#pragma unroll
  for (int r = 0; r < 32; r += 8)
    tile[r + ty][tx] = W[(size_t)(k0 + r + ty) * N + n0 + tx];
  __syncthreads();
#pragma unroll
  for (int r = 0; r < 32; r += 8) {
    float v = tile[tx][r + ty];
    int n = n0 + r + ty, k = k0 + tx;
    u16 h = f2bf(v);
    Th[(size_t)n * K + k] = h;
    Tl[(size_t)n * K + k] = f2bf(v - bf2f(h));
  }
}

// ---------------- bf16x3 MFMA GEMM ----------------

template <bool BIAS, bool RELU, bool OUTPLANES, bool GUARD, bool NT>
__global__ __launch_bounds__(256) void k_mm(MMArgs a, int M, int N, int K) {
  __shared__ __align__(16) char smem[67584];  // staging 64KB | f32 tile 128*132*4
  u16 (*lds)[4][4096] = (u16(*)[4][4096])smem;
  float* ct = (float*)smem;

  int z = blockIdx.z;
  int tid = threadIdx.x;
  int wv = tid >> 6, ln = tid & 63;
  int l15 = ln & 15, l4 = ln >> 4;
  int m0 = blockIdx.x * 128, n0 = blockIdx.y * 128;
  int wm = (wv & 1) * 64, wn = (wv >> 1) * 64;
  const u16* gb = (wv == 0) ? a.Ah[z] : (wv == 1) ? a.Al[z] : (wv == 2) ? a.Bh[z] : a.Bl[z];
  int row0 = (wv < 2) ? m0 : n0;

  f32x4 acc[4][4];
  f32x4 zz = {0.f, 0.f, 0.f, 0.f};
#pragma unroll
  for (int i = 0; i < 4; ++i)
#pragma unroll
    for (int j = 0; j < 4; ++j) acc[i][j] = zz;

  auto stage = [&](int d, int k0) {
#pragma unroll
    for (int it = 0; it < 8; ++it) {
      int slot = it * 64 + ln;
      int r = slot >> 2, c = slot & 3;
      int gc = c ^ ((r >> 2) & 3);
      gload_lds16(gb + ((size_t)(row0 + r) * K + k0 + gc * 8),
                  &lds[d][wv][it * 512]);
    }
  };

  auto compute = [&](int d) {
    bf16x8 ah[4], al[4], bh[4], bl[4];
#pragma unroll
    for (int i = 0; i < 4; ++i) {
      int r = wm + i * 16 + l15;
      int off = r * 32 + ((l4 ^ ((r >> 2) & 3)) << 3);
      ah[i] = *(const bf16x8*)&lds[d][0][off];
      al[i] = *(const bf16x8*)&lds[d][1][off];
    }
#pragma unroll
    for (int j = 0; j < 4; ++j) {
      int r = wn + j * 16 + l15;
      int off = r * 32 + ((l4 ^ ((r >> 2) & 3)) << 3);
      bh[j] = *(const bf16x8*)&lds[d][2][off];
      bl[j] = *(const bf16x8*)&lds[d][3][off];
    }
#pragma unroll
    for (int i = 0; i < 4; ++i)
#pragma unroll
      for (int j = 0; j < 4; ++j) {
        acc[i][j] = __builtin_amdgcn_mfma_f32_16x16x32_bf16(ah[i], bh[j], acc[i][j], 0, 0, 0);
        acc[i][j] = __builtin_amdgcn_mfma_f32_16x16x32_bf16(al[i], bh[j], acc[i][j], 0, 0, 0);
        acc[i][j] = __builtin_amdgcn_mfma_f32_16x16x32_bf16(ah[i], bl[j], acc[i][j], 0, 0, 0);
      }
  };

  stage(0, 0);
  __syncthreads();
  int nk = K >> 5;
  for (int t = 0; t < nk; ++t) {
    int cur = t & 1;
    if (t + 1 < nk) stage(cur ^ 1, (t + 1) << 5);
    compute(cur);
    __syncthreads();
  }

  // ---- epilogue: acc (D layout col=lane&15, row=4*(lane>>4)+reg) -> LDS ----
#pragma unroll
  for (int i = 0; i < 4; ++i)
#pragma unroll
    for (int rr = 0; rr < 4; ++rr) {
      int row = wm + i * 16 + l4 * 4 + rr;
#pragma unroll
      for (int j = 0; j < 4; ++j) {
        int col = wn + l15 + j * 16;
        ct[row * 132 + col] = acc[i][j][rr];
      }
    }
  __syncthreads();

  int tcol = (tid & 31) * 4;
  int trow = tid >> 5;
#pragma unroll
  for (int p = 0; p < 16; ++p) {
    int row = p * 8 + trow;
    int m = m0 + row;
    int n = n0 + tcol;
    if (GUARD && n >= N) continue;
    f32x4 v = *(f32x4*)&ct[row * 132 + tcol];
    float o[4];
#pragma unroll
    for (int e = 0; e < 4; ++e) {
      float x = v[e];
      if (BIAS) x += a.bias[z][n + e];
      if (RELU) x = fmaxf(x, 0.0f);
      o[e] = x;
    }
    if (OUTPLANES) {
      u16x4 hh, ll;
      if (m < M) {
#pragma unroll
        for (int e = 0; e < 4; ++e) {
          u16 h = f2bf(o[e]);
          hh[e] = h;
          ll[e] = f2bf(o[e] - bf2f(h));
        }
      } else {
#pragma unroll
        for (int e = 0; e < 4; ++e) { hh[e] = 0; ll[e] = 0; }
      }
      *(u16x4*)&a.Ch[z][(size_t)m * N + n] = hh;
      *(u16x4*)&a.Cl[z][(size_t)m * N + n] = ll;
    } else {
      if (m < M) {
        f32x4 o4 = {o[0], o[1], o[2], o[3]};
        if (NT)
          __builtin_nontemporal_store(o4, (f32x4*)&a.C[z][(size_t)m * N + n]);
        else
          *(f32x4*)&a.C[z][(size_t)m * N + n] = o4;
      }
    }
  }
}

// ---------------- sparse aggregation: static, z-folded XCD slabs -----------
// Flattened grid 16000: xcd = bid&7 -> z = xcd>>2 (graph), chunk = xcd&3.
// Under round-robin block->XCD dispatch, each XCD gathers exactly ONE
// graph's ONE 128-float chunk slab (8000*128*4B = 4MB = its L2). Streams
// (edata reads, H writes) use nontemporal hints so they don't evict the
// slab. Static single-writer: correctness dispatch-independent (G16); worst
// case degrades to r10 behavior. One wave = one node, float2/lane, LDS edge
// staging (one coalesced load per 64 edges), 4 independent accumulators.

__global__ __launch_bounds__(256) void k_aggregate(AggArgs a) {
  __shared__ int2 ebuf[4][64];
  int bid = blockIdx.x;               // 0..15999
  int xcd = bid & 7;
  int z = xcd >> 2;                   // graph 0 -> XCDs 0-3, graph 1 -> 4-7
  int chunk = xcd & 3;                // 4 chunks x 128 floats (4MB slab)
  int wv = threadIdx.x >> 6, ln = threadIdx.x & 63;
  int c = (bid >> 3) * 4 + wv;        // node 0..7999
  int fo = chunk * 128 + ln * 2;
  const float* XW = a.XW[z];
  const i64* ed = (const i64*)a.edata[z];
  int e0 = a.colptr[z][c], e1 = a.colptr[z][c + 1];
  float di = a.dinv[z][c];
  float sl = di * di;

  float2 self = *(const float2*)&XW[(size_t)c * FF + fo];
  float x0 = self.x * sl, y0 = self.y * sl;
  float x1 = 0.f, y1 = 0.f, x2 = 0.f, y2 = 0.f, x3 = 0.f, y3 = 0.f;

  for (int base = e0; base < e1; base += 64) {
    if (base + ln < e1) {
      i64 v = __builtin_nontemporal_load(&ed[base + ln]);
      ebuf[wv][ln] = make_int2((int)(v & 0xffffffffLL), (int)(v >> 32));
    }
    int rem = e1 - base;
    int ne = rem < 64 ? rem : 64;
    int j = 0;
    for (; j + 4 <= ne; j += 4) {
      int2 d0 = ebuf[wv][j], d1 = ebuf[wv][j + 1];
      int2 d2 = ebuf[wv][j + 2], d3 = ebuf[wv][j + 3];
      float2 u0 = *(const float2*)&XW[(size_t)d0.x * FF + fo];
      float2 u1 = *(const float2*)&XW[(size_t)d1.x * FF + fo];
      float2 u2 = *(const float2*)&XW[(size_t)d2.x * FF + fo];
      float2 u3 = *(const float2*)&XW[(size_t)d3.x * FF + fo];
      float w0 = __int_as_float(d0.y), w1 = __int_as_float(d1.y);
      float w2 = __int_as_float(d2.y), w3 = __int_as_float(d3.y);
      x0 = fmaf(w0, u0.x, x0); y0 = fmaf(w0, u0.y, y0);
      x1 = fmaf(w1, u1.x, x1); y1 = fmaf(w1, u1.y, y1);
      x2 = fmaf(w2, u2.x, x2); y2 = fmaf(w2, u2.y, y2);
      x3 = fmaf(w3, u3.x, x3); y3 = fmaf(w3, u3.y, y3);
    }
    for (; j < ne; ++j) {
      int2 d0 = ebuf[wv][j];
      float2 u0 = *(const float2*)&XW[(size_t)d0.x * FF + fo];
      float w0 = __int_as_float(d0.y);
      x0 = fmaf(w0, u0.x, x0); y0 = fmaf(w0, u0.y, y0);
    }
  }

  float2 b2 = *(const float2*)&a.bias[z][fo];
  float ox = fmaxf((x0 + x1) + (x2 + x3) + b2.x, 0.0f);
  float oy = fmaxf((y0 + y1) + (y2 + y3) + b2.y, 0.0f);
  u16 hx = f2bf(ox), hy = f2bf(oy);
  u32 hbits = (u32)hx | ((u32)hy << 16);
  u32 lbits = (u32)f2bf(ox - bf2f(hx)) | ((u32)f2bf(oy - bf2f(hy)) << 16);
  __builtin_nontemporal_store(hbits, (u32*)&a.Hh[z][(size_t)c * FF + fo]);
  __builtin_nontemporal_store(lbits, (u32*)&a.Hl[z][(size_t)c * FF + fo]);
}

// ---------------- host orchestration ----------------

extern "C" void kernel_launch(void* const* d_in, const int* in_sizes, int n_in,
                              void* d_out, int out_size, void* d_ws, size_t ws_size,
                              hipStream_t stream) {
  const float* x_m    = (const float*)d_in[0];
  const float* x_d    = (const float*)d_in[1];
  const float* data_m = (const float*)d_in[2];
  const float* data_d = (const float*)d_in[3];
  const int*   ei_m   = (const int*)d_in[4];
  const int*   ei_d   = (const int*)d_in[5];
  const float* Wg1 = (const float*)d_in[6];
  const float* bg1 = (const float*)d_in[7];
  const float* Wg2 = (const float*)d_in[8];
  const float* bg2 = (const float*)d_in[9];
  const float* Wd1 = (const float*)d_in[10];
  const float* bd1 = (const float*)d_in[11];
  const float* Wd2 = (const float*)d_in[12];
  const float* bd2 = (const float*)d_in[13];
  const float* lx1_w = (const float*)d_in[14];
  const float* lx1_b = (const float*)d_in[15];
  const float* lx2_w = (const float*)d_in[16];
  const float* lx2_b = (const float*)d_in[17];
  const float* lx3_w = (const float*)d_in[18];
  const float* lx3_b = (const float*)d_in[19];
  const float* ly1_w = (const float*)d_in[20];
  const float* ly1_b = (const float*)d_in[21];
  const float* ly2_w = (const float*)d_in[22];
  const float* ly2_b = (const float*)d_in[23];
  const float* ly3_w = (const float*)d_in[24];
  const float* ly3_b = (const float*)d_in[25];
  float* out = (float*)d_out;

  char* base = (char*)d_ws;
  size_t off = 0;
  auto alloc = [&](size_t bytes) -> char* {
    char* p = base + off;
    off += (bytes + 255) & ~(size_t)255;
    return p;
  };
  u16* hh[2], *hl[2];
  for (int z = 0; z < 2; ++z) {
    hh[z] = (u16*)alloc((size_t)MP * FF * 2);
    hl[z] = (u16*)alloc((size_t)MP * FF * 2);
  }
  u16* p1h[2], *p1l[2], *p2h[2], *p2l[2], *fh[2], *fl[2];
  for (int z = 0; z < 2; ++z) {
    p1h[z] = (u16*)alloc((size_t)MP * 256 * 2);
    p1l[z] = (u16*)alloc((size_t)MP * 256 * 2);
    p2h[z] = (u16*)alloc((size_t)MP * 128 * 2);
    p2l[z] = (u16*)alloc((size_t)MP * 128 * 2);
    fh[z]  = (u16*)alloc((size_t)MP * 64 * 2);
    fl[z]  = (u16*)alloc((size_t)MP * 64 * 2);
  }
  float* bufA[2];
  for (int z = 0; z < 2; ++z) bufA[z] = (float*)alloc((size_t)NN * FF * 4);
  u16 *wg1h[2], *wg1l[2], *wg2h[2], *wg2l[2], *wl1h[2], *wl1l[2],
      *wl2h[2], *wl2l[2], *wl3h[2], *wl3l[2];
  for (int z = 0; z < 2; ++z) {
    wg1h[z] = (u16*)alloc((size_t)512 * 512 * 2);
    wg1l[z] = (u16*)alloc((size_t)512 * 512 * 2);
    wg2h[z] = (u16*)alloc((size_t)512 * 512 * 2);
    wg2l[z] = (u16*)alloc((size_t)512 * 512 * 2);
    wl1h[z] = (u16*)alloc((size_t)512 * 256 * 2);
    wl1l[z] = (u16*)alloc((size_t)512 * 256 * 2);
    wl2h[z] = (u16*)alloc((size_t)256 * 128 * 2);
    wl2l[z] = (u16*)alloc((size_t)256 * 128 * 2);
    wl3h[z] = (u16*)alloc((size_t)128 * 64 * 2);
    wl3l[z] = (u16*)alloc((size_t)128 * 64 * 2);
  }
  PreArgs P;
  for (int z = 0; z < 2; ++z) {
    P.data[z]   = z ? data_d : data_m;
    P.ei[z]     = z ? ei_d : ei_m;
    P.wbuf[z]   = (float*)alloc((size_t)NE * 4);
    P.edata[z]  = (int2*)alloc((size_t)NE * 8);
    P.deg[z]    = (float*)alloc((size_t)NN * 4);
    P.dinv[z]   = (float*)alloc((size_t)NN * 4);
    P.cnt[z]    = (int*)alloc((size_t)NN * 4);
    P.colptr[z] = (int*)alloc((size_t)(NN + 1) * 4);
  }

  // ---- setup: split acts + init deg/cnt ----
  SetupArgs S;
  S.x[0] = x_m; S.x[1] = x_d;
  for (int z = 0; z < 2; ++z) {
    S.ph[z] = hh[z]; S.pl[z] = hl[z];
    S.deg[z] = P.deg[z]; S.cnt[z] = P.cnt[z];
  }
  int sb = (MP * FF / 4 + 255) / 256;
  int nb = (NN + 255) / 256;
  int eb = (NE + 255) / 256;
  k_setup<<<dim3(sb + nb, 1, 2), 256, 0, stream>>>(S, sb, NN * FF, MP * FF);
  k_edge_w<<<dim3(eb, 1, 2), 256, 0, stream>>>(P, NE, NN);
  k_scan_dinv<<<dim3(1, 1, 2), 256, 0, stream>>>(P, NN);
  k_scatter<<<dim3(eb, 1, 2), 256, 0, stream>>>(P, NE);

  // ---- all weight splits in one launch ----
  WTAll WA;
  const float* Wsrc[10] = {Wg1, Wg2, lx1_w, lx2_w, lx3_w, Wd1, Wd2, ly1_w, ly2_w, ly3_w};
  u16* Thd[10] = {wg1h[0], wg2h[0], wl1h[0], wl2h[0], wl3h[0],
                  wg1h[1], wg2h[1], wl1h[1], wl2h[1], wl3h[1]};
  u16* Tld[10] = {wg1l[0], wg2l[0], wl1l[0], wl2l[0], wl3l[0],
                  wg1l[1], wg2l[1], wl1l[1], wl2l[1], wl3l[1]};
  int Ks[10] = {512, 512, 512, 256, 128, 512, 512, 512, 256, 128};
  int Ns[10] = {512, 512, 256, 128, 64, 512, 512, 256, 128, 64};
  int acc_t = 0;
  for (int m = 0; m < 10; ++m) {
    WA.W[m] = Wsrc[m]; WA.Th[m] = Thd[m]; WA.Tl[m] = Tld[m];
    WA.K[m] = Ks[m]; WA.N[m] = Ns[m];
    WA.toff[m] = acc_t;
    acc_t += (Ns[m] / 32) * (Ks[m] / 32);
  }
  WA.toff[10] = acc_t;
  k_splitW_all<<<acc_t, 256, 0, stream>>>(WA);

  MMArgs MA;
  AggArgs GA;
  for (int z = 0; z < 2; ++z) {
    MA.bias[z] = nullptr; MA.C[z] = nullptr; MA.Ch[z] = nullptr; MA.Cl[z] = nullptr;
    GA.XW[z] = bufA[z];
    GA.colptr[z] = P.colptr[z];
    GA.edata[z] = P.edata[z];
    GA.dinv[z] = P.dinv[z];
    GA.Hh[z] = hh[z]; GA.Hl[z] = hl[z];
  }

  // ---- GCN layer 1 ----
  for (int z = 0; z < 2; ++z) {
    MA.Ah[z] = hh[z]; MA.Al[z] = hl[z];
    MA.Bh[z] = wg1h[z]; MA.Bl[z] = wg1l[z];
    MA.C[z] = bufA[z];
  }
  k_mm<false, false, false, false, false><<<dim3(63, FF / 128, 2), 256, 0, stream>>>(MA, NN, FF, FF);
  GA.bias[0] = bg1; GA.bias[1] = bd1;
  k_aggregate<<<dim3(16000, 1, 1), 256, 0, stream>>>(GA);

  // ---- GCN layer 2 ----
  for (int z = 0; z < 2; ++z) { MA.Bh[z] = wg2h[z]; MA.Bl[z] = wg2l[z]; }
  k_mm<false, false, false, false, false><<<dim3(63, FF / 128, 2), 256, 0, stream>>>(MA, NN, FF, FF);
  GA.bias[0] = bg2; GA.bias[1] = bd2;
  k_aggregate<<<dim3(16000, 1, 1), 256, 0, stream>>>(GA);

  // ---- MLP1: 512 -> 256, planes out ----
  MA.bias[0] = lx1_b; MA.bias[1] = ly1_b;
  for (int z = 0; z < 2; ++z) {
    MA.Bh[z] = wl1h[z]; MA.Bl[z] = wl1l[z];
    MA.Ch[z] = p1h[z]; MA.Cl[z] = p1l[z];
  }
  k_mm<true, true, true, false, false><<<dim3(63, 2, 2), 256, 0, stream>>>(MA, NN, 256, FF);

  // ---- MLP2: 256 -> 128 ----
  MA.bias[0] = lx2_b; MA.bias[1] = ly2_b;
  for (int z = 0; z < 2; ++z) {
    MA.Ah[z] = p1h[z]; MA.Al[z] = p1l[z];
    MA.Bh[z] = wl2h[z]; MA.Bl[z] = wl2l[z];
    MA.Ch[z] = p2h[z]; MA.Cl[z] = p2l[z];
  }
  k_mm<true, true, true, false, false><<<dim3(63, 1, 2), 256, 0, stream>>>(MA, NN, 128, 256);

  // ---- MLP3: 128 -> 64 (N-guard) ----
  MA.bias[0] = lx3_b; MA.bias[1] = ly3_b;
  for (int z = 0; z < 2; ++z) {
    MA.Ah[z] = p2h[z]; MA.Al[z] = p2l[z];
    MA.Bh[z] = wl3h[z]; MA.Bl[z] = wl3l[z];
    MA.Ch[z] = fh[z]; MA.Cl[z] = fl[z];
  }
  k_mm<true, true, true, true, false><<<dim3(63, 1, 2), 256, 0, stream>>>(MA, NN, 64, 128);

  // ---- scores = x @ y^T (nontemporal 256 MB write) ----
  MMArgs SC;
  SC.Ah[0] = fh[0]; SC.Al[0] = fl[0];
  SC.Bh[0] = fh[1]; SC.Bl[0] = fl[1];
  SC.Ah[1] = SC.Ah[0]; SC.Al[1] = SC.Al[0]; SC.Bh[1] = SC.Bh[0]; SC.Bl[1] = SC.Bl[0];
  SC.bias[0] = nullptr; SC.bias[1] = nullptr;
  SC.C[0] = out; SC.C[1] = out;
  SC.Ch[0] = SC.Ch[1] = nullptr; SC.Cl[0] = SC.Cl[1] = nullptr;
  k_mm<false, false, false, true, true><<<dim3(63, 63, 1), 256, 0, stream>>>(SC, NN, NN, 64);
}

// Round 12
// 393.813 us; speedup vs baseline: 1.1892x; 1.1892x over previous
//
#include <hip/hip_runtime.h>

typedef unsigned short u16;
typedef unsigned int u32;
typedef __attribute__((ext_vector_type(8))) short bf16x8;
typedef __attribute__((ext_vector_type(4))) float f32x4;
typedef __attribute__((ext_vector_type(4))) unsigned short u16x4;
typedef __attribute__((ext_vector_type(2))) unsigned short u16x2;

static const int NN = 8000;    // nodes per graph (M == D)
static const int NE = 256000;  // edges per graph
static const int FF = 512;     // feature dim
static const int MP = 8064;    // 63 * 128 padded rows

__device__ __forceinline__ u16 f2bf(float x) {
  union { float f; u32 u; } a; a.f = x;
  u32 r = a.u + 0x7FFF + ((a.u >> 16) & 1);  // RNE
  return (u16)(r >> 16);
}
__device__ __forceinline__ float bf2f(u16 b) {
  union { float f; u32 u; } a; a.u = ((u32)b) << 16;
  return a.f;
}

__device__ __forceinline__ void gload_lds16(const void* g, void* l) {
  __builtin_amdgcn_global_load_lds(
      (const __attribute__((address_space(1))) unsigned int*)g,
      (__attribute__((address_space(3))) unsigned int*)l, 16, 0, 0);
}

// ---------------- arg structs (blockIdx.z = graph where applicable) --------

struct SetupArgs {
  const float* x[2];
  u16* ph[2];
  u16* pl[2];
  float* deg[2];
  int* cnt[2];
};

struct PreArgs {
  const float* data[2];
  const int* ei[2];
  float* wbuf[2];
  float* deg[2];
  int* cnt[2];
  float* dinv[2];
  int* colptr[2];
  int2* edata[2];  // packed (src, norm-bits)
};

struct WTAll {
  const float* W[10];
  u16* Th[10];
  u16* Tl[10];
  int K[10], N[10];
  int toff[11];
};

struct MMArgs {
  const u16* Ah[2]; const u16* Al[2];
  const u16* Bh[2]; const u16* Bl[2];
  const float* bias[2];
  float* C[2];             // fp32 output (OUTMODE 0)
  u16* Ch[2]; u16* Cl[2];  // plane outputs (OUTMODE 1 = hi+lo, 2 = hi only)
};

struct AggArgs {
  const u16* XWh[2];       // bf16-hi XW planes [MP][FF]
  const int* colptr[2];
  const int2* edata[2];
  const float* dinv[2];
  const float* bias[2];
  u16* Hh[2];
  u16* Hl[2];
};

// ---------------- setup: split input acts + init deg/cnt ----------------

__global__ __launch_bounds__(256) void k_setup(SetupArgs s, int sb, int tot_in, int tot_pad) {
  int z = blockIdx.z;
  int b = blockIdx.x;
  int tid = threadIdx.x;
  if (b < sb) {
    int i = (b * 256 + tid) * 4;
    if (i >= tot_pad) return;
    float4 v = (i < tot_in) ? *(const float4*)&s.x[z][i] : make_float4(0.f, 0.f, 0.f, 0.f);
    u16x4 h, l;
#pragma unroll
    for (int e = 0; e < 4; ++e) {
      float x = (&v.x)[e];
      u16 hh = f2bf(x);
      h[e] = hh;
      l[e] = f2bf(x - bf2f(hh));
    }
    *(u16x4*)&s.ph[z][i] = h;
    *(u16x4*)&s.pl[z][i] = l;
  } else {
    int i = (b - sb) * 256 + tid;
    if (i < NN) { s.deg[z][i] = 1.0f; s.cnt[z][i] = 0; }
  }
}

// ---------------- edge weights + degree ----------------

__global__ __launch_bounds__(256) void k_edge_w(PreArgs p, int E, int n) {
  int z = blockIdx.z;
  int e = blockIdx.x * 256 + threadIdx.x;
  if (e >= E) return;
  const int* ei = p.ei[z];
  int r = ei[e];
  int c = ei[E + e];
  float w = fmaxf(p.data[z][(size_t)r * n + c], 0.0f);
  p.wbuf[z][e] = w;
  atomicAdd(&p.deg[z][c], w);
  atomicAdd(&p.cnt[z][c], 1);
}

// one block per z: dinv + exclusive scan of cnt -> colptr; zero cnt
__global__ __launch_bounds__(256) void k_scan_dinv(PreArgs p, int n) {
  int z = blockIdx.z;
  const int* cnt = p.cnt[z];
  int* colptr = p.colptr[z];
  int* cntz = p.cnt[z];
  __shared__ int part[256];
  int t = threadIdx.x;
  const int CH = 32;
  int base = t * CH;
  for (int i = 0; i < CH; ++i) {
    int idx = base + i;
    if (idx < n) p.dinv[z][idx] = 1.0f / sqrtf(p.deg[z][idx]);
  }
  int local[CH];
  int s = 0;
  for (int i = 0; i < CH; ++i) {
    int idx = base + i;
    int v = (idx < n) ? cnt[idx] : 0;
    local[i] = s;
    s += v;
  }
  part[t] = s;
  __syncthreads();
  for (int o = 1; o < 256; o <<= 1) {
    int v = (t >= o) ? part[t - o] : 0;
    __syncthreads();
    part[t] += v;
    __syncthreads();
  }
  int pre = (t == 0) ? 0 : part[t - 1];
  for (int i = 0; i < CH; ++i) {
    int idx = base + i;
    if (idx < n) { colptr[idx] = pre + local[i]; cntz[idx] = 0; }
  }
  if (t == 255) colptr[n] = part[255];
}

__global__ __launch_bounds__(256) void k_scatter(PreArgs p, int E) {
  int z = blockIdx.z;
  int e = blockIdx.x * 256 + threadIdx.x;
  if (e >= E) return;
  const int* ei = p.ei[z];
  int r = ei[e], c = ei[E + e];
  int pos = p.colptr[z][c] + atomicAdd(&p.cnt[z][c], 1);
  int2 sn;
  sn.x = r;
  sn.y = __float_as_int(p.dinv[z][r] * p.wbuf[z][e] * p.dinv[z][c]);
  p.edata[z][pos] = sn;
}

// ---------------- all weight transposes+splits in one launch ----------------
// W [K][N] -> Th/Tl [N][K] for 10 matrices.

__global__ __launch_bounds__(256) void k_splitW_all(WTAll a) {
  int bid = blockIdx.x;
  int m = 0;
  while (bid >= a.toff[m + 1]) ++m;
  int local = bid - a.toff[m];
  int K = a.K[m], N = a.N[m];
  int ntn = N >> 5;
  int n0 = (local % ntn) * 32, k0 = (local / ntn) * 32;
  const float* W = a.W[m];
  u16* Th = a.Th[m];
  u16* Tl = a.Tl[m];
  __shared__ float tile[32][33];
  int tx = threadIdx.x & 31, ty = threadIdx.x >> 5;
#pragma unroll
  for (int r = 0; r < 32; r += 8)
    tile[r + ty][tx] = W[(size_t)(k0 + r + ty) * N + n0 + tx];
  __syncthreads();
#pragma unroll
  for (int r = 0; r < 32; r += 8) {
    float v = tile[tx][r + ty];
    int n = n0 + r + ty, k = k0 + tx;
    u16 h = f2bf(v);
    Th[(size_t)n * K + k] = h;
    Tl[(size_t)n * K + k] = f2bf(v - bf2f(h));
  }
}

// ---------------- bf16x3 MFMA GEMM ----------------
// OUTMODE: 0 = fp32 C, 1 = bf16 hi+lo planes, 2 = bf16 hi-only plane.

template <bool BIAS, bool RELU, int OUTMODE, bool GUARD, bool NT>
__global__ __launch_bounds__(256) void k_mm(MMArgs a, int M, int N, int K) {
  __shared__ __align__(16) char smem[67584];  // staging 64KB | f32 tile 128*132*4
  u16 (*lds)[4][4096] = (u16(*)[4][4096])smem;
  float* ct = (float*)smem;

  int z = blockIdx.z;
  int tid = threadIdx.x;
  int wv = tid >> 6, ln = tid & 63;
  int l15 = ln & 15, l4 = ln >> 4;
  int m0 = blockIdx.x * 128, n0 = blockIdx.y * 128;
  int wm = (wv & 1) * 64, wn = (wv >> 1) * 64;
  const u16* gb = (wv == 0) ? a.Ah[z] : (wv == 1) ? a.Al[z] : (wv == 2) ? a.Bh[z] : a.Bl[z];
  int row0 = (wv < 2) ? m0 : n0;

  f32x4 acc[4][4];
  f32x4 zz = {0.f, 0.f, 0.f, 0.f};
#pragma unroll
  for (int i = 0; i < 4; ++i)
#pragma unroll
    for (int j = 0; j < 4; ++j) acc[i][j] = zz;

  auto stage = [&](int d, int k0) {
#pragma unroll
    for (int it = 0; it < 8; ++it) {
      int slot = it * 64 + ln;
      int r = slot >> 2, c = slot & 3;
      int gc = c ^ ((r >> 2) & 3);
      gload_lds16(gb + ((size_t)(row0 + r) * K + k0 + gc * 8),
                  &lds[d][wv][it * 512]);
    }
  };

  auto compute = [&](int d) {
    bf16x8 ah[4], al[4], bh[4], bl[4];
#pragma unroll
    for (int i = 0; i < 4; ++i) {
      int r = wm + i * 16 + l15;
      int off = r * 32 + ((l4 ^ ((r >> 2) & 3)) << 3);
      ah[i] = *(const bf16x8*)&lds[d][0][off];
      al[i] = *(const bf16x8*)&lds[d][1][off];
    }
#pragma unroll
    for (int j = 0; j < 4; ++j) {
      int r = wn + j * 16 + l15;
      int off = r * 32 + ((l4 ^ ((r >> 2) & 3)) << 3);
      bh[j] = *(const bf16x8*)&lds[d][2][off];
      bl[j] = *(const bf16x8*)&lds[d][3][off];
    }
#pragma unroll
    for (int i = 0; i < 4; ++i)
#pragma unroll
      for (int j = 0; j < 4; ++j) {
        acc[i][j] = __builtin_amdgcn_mfma_f32_16x16x32_bf16(ah[i], bh[j], acc[i][j], 0, 0, 0);
        acc[i][j] = __builtin_amdgcn_mfma_f32_16x16x32_bf16(al[i], bh[j], acc[i][j], 0, 0, 0);
        acc[i][j] = __builtin_amdgcn_mfma_f32_16x16x32_bf16(ah[i], bl[j], acc[i][j], 0, 0, 0);
      }
  };

  stage(0, 0);
  __syncthreads();
  int nk = K >> 5;
  for (int t = 0; t < nk; ++t) {
    int cur = t & 1;
    if (t + 1 < nk) stage(cur ^ 1, (t + 1) << 5);
    compute(cur);
    __syncthreads();
  }

  // ---- epilogue: acc (D layout col=lane&15, row=4*(lane>>4)+reg) -> LDS ----
#pragma unroll
  for (int i = 0; i < 4; ++i)
#pragma unroll
    for (int rr = 0; rr < 4; ++rr) {
      int row = wm + i * 16 + l4 * 4 + rr;
#pragma unroll
      for (int j = 0; j < 4; ++j) {
        int col = wn + l15 + j * 16;
        ct[row * 132 + col] = acc[i][j][rr];
      }
    }
  __syncthreads();

  int tcol = (tid & 31) * 4;
  int trow = tid >> 5;
#pragma unroll
  for (int p = 0; p < 16; ++p) {
    int row = p * 8 + trow;
    int m = m0 + row;
    int n = n0 + tcol;
    if (GUARD && n >= N) continue;
    f32x4 v = *(f32x4*)&ct[row * 132 + tcol];
    float o[4];
#pragma unroll
    for (int e = 0; e < 4; ++e) {
      float x = v[e];
      if (BIAS) x += a.bias[z][n + e];
      if (RELU) x = fmaxf(x, 0.0f);
      o[e] = x;
    }
    if (OUTMODE >= 1) {
      u16x4 hh, ll;
      if (m < M) {
#pragma unroll
        for (int e = 0; e < 4; ++e) {
          u16 h = f2bf(o[e]);
          hh[e] = h;
          if (OUTMODE == 1) ll[e] = f2bf(o[e] - bf2f(h));
        }
      } else {
#pragma unroll
        for (int e = 0; e < 4; ++e) { hh[e] = 0; ll[e] = 0; }
      }
      *(u16x4*)&a.Ch[z][(size_t)m * N + n] = hh;
      if (OUTMODE == 1) *(u16x4*)&a.Cl[z][(size_t)m * N + n] = ll;
    } else {
      if (m < M) {
        f32x4 o4 = {o[0], o[1], o[2], o[3]};
        if (NT)
          __builtin_nontemporal_store(o4, (f32x4*)&a.C[z][(size_t)m * N + n]);
        else
          *(f32x4*)&a.C[z][(size_t)m * N + n] = o4;
      }
    }
  }
}

// ---------------- sparse aggregation: static, bf16 gathers, L2 slabs -------
// XW gathered as bf16-hi (2B/elem): half the traffic of fp32, and chunk
// slab = 8000*128*2B = 2MB, so both graphs' slabs (4MB) fit one XCD L2
// under the r10 chunk = bid&3 mapping. One wave = one (node, 128-elem
// chunk); u16x2 per lane (256B/wave/edge = 2 cache lines). LDS edge staging
// (one coalesced load per 64 edges), 4 independent accumulator pairs, no
// atomics; static single-writer mapping (G16-safe). Accumulate fp32.

__global__ __launch_bounds__(256) void k_aggregate(AggArgs a) {
  __shared__ int2 ebuf[4][64];
  int z = blockIdx.z;
  int bid = blockIdx.x;               // 0..7999
  int wv = threadIdx.x >> 6, ln = threadIdx.x & 63;
  int chunk = bid & 3;                // 4 chunks x 128 elems (2MB slab)
  int c = (bid >> 2) * 4 + wv;        // node 0..7999
  int fo = chunk * 128 + ln * 2;
  const u16* XWh = a.XWh[z];
  const int2* ed = a.edata[z];
  int e0 = a.colptr[z][c], e1 = a.colptr[z][c + 1];
  float di = a.dinv[z][c];
  float sl = di * di;

  u16x2 sh = *(const u16x2*)&XWh[(size_t)c * FF + fo];
  float x0 = bf2f(sh[0]) * sl, y0 = bf2f(sh[1]) * sl;
  float x1 = 0.f, y1 = 0.f, x2 = 0.f, y2 = 0.f, x3 = 0.f, y3 = 0.f;

  for (int base = e0; base < e1; base += 64) {
    if (base + ln < e1) ebuf[wv][ln] = ed[base + ln];
    int rem = e1 - base;
    int ne = rem < 64 ? rem : 64;
    int j = 0;
    for (; j + 4 <= ne; j += 4) {
      int2 d0 = ebuf[wv][j], d1 = ebuf[wv][j + 1];
      int2 d2 = ebuf[wv][j + 2], d3 = ebuf[wv][j + 3];
      u16x2 q0 = *(const u16x2*)&XWh[(size_t)d0.x * FF + fo];
      u16x2 q1 = *(const u16x2*)&XWh[(size_t)d1.x * FF + fo];
      u16x2 q2 = *(const u16x2*)&XWh[(size_t)d2.x * FF + fo];
      u16x2 q3 = *(const u16x2*)&XWh[(size_t)d3.x * FF + fo];
      float w0 = __int_as_float(d0.y), w1 = __int_as_float(d1.y);
      float w2 = __int_as_float(d2.y), w3 = __int_as_float(d3.y);
      x0 = fmaf(w0, bf2f(q0[0]), x0); y0 = fmaf(w0, bf2f(q0[1]), y0);
      x1 = fmaf(w1, bf2f(q1[0]), x1); y1 = fmaf(w1, bf2f(q1[1]), y1);
      x2 = fmaf(w2, bf2f(q2[0]), x2); y2 = fmaf(w2, bf2f(q2[1]), y2);
      x3 = fmaf(w3, bf2f(q3[0]), x3); y3 = fmaf(w3, bf2f(q3[1]), y3);
    }
    for (; j < ne; ++j) {
      int2 d0 = ebuf[wv][j];
      u16x2 q0 = *(const u16x2*)&XWh[(size_t)d0.x * FF + fo];
      float w0 = __int_as_float(d0.y);
      x0 = fmaf(w0, bf2f(q0[0]), x0); y0 = fmaf(w0, bf2f(q0[1]), y0);
    }
  }

  float2 b2 = *(const float2*)&a.bias[z][fo];
  float ox = fmaxf((x0 + x1) + (x2 + x3) + b2.x, 0.0f);
  float oy = fmaxf((y0 + y1) + (y2 + y3) + b2.y, 0.0f);
  u16 hx = f2bf(ox), hy = f2bf(oy);
  u16x2 hh = {hx, hy};
  u16x2 ll = {f2bf(ox - bf2f(hx)), f2bf(oy - bf2f(hy))};
  *(u16x2*)&a.Hh[z][(size_t)c * FF + fo] = hh;
  *(u16x2*)&a.Hl[z][(size_t)c * FF + fo] = ll;
}

// ---------------- host orchestration ----------------

extern "C" void kernel_launch(void* const* d_in, const int* in_sizes, int n_in,
                              void* d_out, int out_size, void* d_ws, size_t ws_size,
                              hipStream_t stream) {
  const float* x_m    = (const float*)d_in[0];
  const float* x_d    = (const float*)d_in[1];
  const float* data_m = (const float*)d_in[2];
  const float* data_d = (const float*)d_in[3];
  const int*   ei_m   = (const int*)d_in[4];
  const int*   ei_d   = (const int*)d_in[5];
  const float* Wg1 = (const float*)d_in[6];
  const float* bg1 = (const float*)d_in[7];
  const float* Wg2 = (const float*)d_in[8];
  const float* bg2 = (const float*)d_in[9];
  const float* Wd1 = (const float*)d_in[10];
  const float* bd1 = (const float*)d_in[11];
  const float* Wd2 = (const float*)d_in[12];
  const float* bd2 = (const float*)d_in[13];
  const float* lx1_w = (const float*)d_in[14];
  const float* lx1_b = (const float*)d_in[15];
  const float* lx2_w = (const float*)d_in[16];
  const float* lx2_b = (const float*)d_in[17];
  const float* lx3_w = (const float*)d_in[18];
  const float* lx3_b = (const float*)d_in[19];
  const float* ly1_w = (const float*)d_in[20];
  const float* ly1_b = (const float*)d_in[21];
  const float* ly2_w = (const float*)d_in[22];
  const float* ly2_b = (const float*)d_in[23];
  const float* ly3_w = (const float*)d_in[24];
  const float* ly3_b = (const float*)d_in[25];
  float* out = (float*)d_out;

  char* base = (char*)d_ws;
  size_t off = 0;
  auto alloc = [&](size_t bytes) -> char* {
    char* p = base + off;
    off += (bytes + 255) & ~(size_t)255;
    return p;
  };
  u16* hh[2], *hl[2];
  for (int z = 0; z < 2; ++z) {
    hh[z] = (u16*)alloc((size_t)MP * FF * 2);
    hl[z] = (u16*)alloc((size_t)MP * FF * 2);
  }
  u16* xwh[2];  // bf16-hi XW (GCN GEMM output / aggregation input)
  for (int z = 0; z < 2; ++z) xwh[z] = (u16*)alloc((size_t)MP * FF * 2);
  u16* p1h[2], *p1l[2], *p2h[2], *p2l[2], *fh[2], *fl[2];
  for (int z = 0; z < 2; ++z) {
    p1h[z] = (u16*)alloc((size_t)MP * 256 * 2);
    p1l[z] = (u16*)alloc((size_t)MP * 256 * 2);
    p2h[z] = (u16*)alloc((size_t)MP * 128 * 2);
    p2l[z] = (u16*)alloc((size_t)MP * 128 * 2);
    fh[z]  = (u16*)alloc((size_t)MP * 64 * 2);
    fl[z]  = (u16*)alloc((size_t)MP * 64 * 2);
  }
  u16 *wg1h[2], *wg1l[2], *wg2h[2], *wg2l[2], *wl1h[2], *wl1l[2],
      *wl2h[2], *wl2l[2], *wl3h[2], *wl3l[2];
  for (int z = 0; z < 2; ++z) {
    wg1h[z] = (u16*)alloc((size_t)512 * 512 * 2);
    wg1l[z] = (u16*)alloc((size_t)512 * 512 * 2);
    wg2h[z] = (u16*)alloc((size_t)512 * 512 * 2);
    wg2l[z] = (u16*)alloc((size_t)512 * 512 * 2);
    wl1h[z] = (u16*)alloc((size_t)512 * 256 * 2);
    wl1l[z] = (u16*)alloc((size_t)512 * 256 * 2);
    wl2h[z] = (u16*)alloc((size_t)256 * 128 * 2);
    wl2l[z] = (u16*)alloc((size_t)256 * 128 * 2);
    wl3h[z] = (u16*)alloc((size_t)128 * 64 * 2);
    wl3l[z] = (u16*)alloc((size_t)128 * 64 * 2);
  }
  PreArgs P;
  for (int z = 0; z < 2; ++z) {
    P.data[z]   = z ? data_d : data_m;
    P.ei[z]     = z ? ei_d : ei_m;
    P.wbuf[z]   = (float*)alloc((size_t)NE * 4);
    P.edata[z]  = (int2*)alloc((size_t)NE * 8);
    P.deg[z]    = (float*)alloc((size_t)NN * 4);
    P.dinv[z]   = (float*)alloc((size_t)NN * 4);
    P.cnt[z]    = (int*)alloc((size_t)NN * 4);
    P.colptr[z] = (int*)alloc((size_t)(NN + 1) * 4);
  }

  // ---- setup: split acts + init deg/cnt ----
  SetupArgs S;
  S.x[0] = x_m; S.x[1] = x_d;
  for (int z = 0; z < 2; ++z) {
    S.ph[z] = hh[z]; S.pl[z] = hl[z];
    S.deg[z] = P.deg[z]; S.cnt[z] = P.cnt[z];
  }
  int sb = (MP * FF / 4 + 255) / 256;
  int nb = (NN + 255) / 256;
  int eb = (NE + 255) / 256;
  k_setup<<<dim3(sb + nb, 1, 2), 256, 0, stream>>>(S, sb, NN * FF, MP * FF);
  k_edge_w<<<dim3(eb, 1, 2), 256, 0, stream>>>(P, NE, NN);
  k_scan_dinv<<<dim3(1, 1, 2), 256, 0, stream>>>(P, NN);
  k_scatter<<<dim3(eb, 1, 2), 256, 0, stream>>>(P, NE);

  // ---- all weight splits in one launch ----
  WTAll WA;
  const float* Wsrc[10] = {Wg1, Wg2, lx1_w, lx2_w, lx3_w, Wd1, Wd2, ly1_w, ly2_w, ly3_w};
  u16* Thd[10] = {wg1h[0], wg2h[0], wl1h[0], wl2h[0], wl3h[0],
                  wg1h[1], wg2h[1], wl1h[1], wl2h[1], wl3h[1]};
  u16* Tld[10] = {wg1l[0], wg2l[0], wl1l[0], wl2l[0], wl3l[0],
                  wg1l[1], wg2l[1], wl1l[1], wl2l[1], wl3l[1]};
  int Ks[10] = {512, 512, 512, 256, 128, 512, 512, 512, 256, 128};
  int Ns[10] = {512, 512, 256, 128, 64, 512, 512, 256, 128, 64};
  int acc_t = 0;
  for (int m = 0; m < 10; ++m) {
    WA.W[m] = Wsrc[m]; WA.Th[m] = Thd[m]; WA.Tl[m] = Tld[m];
    WA.K[m] = Ks[m]; WA.N[m] = Ns[m];
    WA.toff[m] = acc_t;
    acc_t += (Ns[m] / 32) * (Ks[m] / 32);
  }
  WA.toff[10] = acc_t;
  k_splitW_all<<<acc_t, 256, 0, stream>>>(WA);

  MMArgs MA;
  AggArgs GA;
  for (int z = 0; z < 2; ++z) {
    MA.bias[z] = nullptr; MA.C[z] = nullptr; MA.Ch[z] = nullptr; MA.Cl[z] = nullptr;
    GA.XWh[z] = xwh[z];
    GA.colptr[z] = P.colptr[z];
    GA.edata[z] = P.edata[z];
    GA.dinv[z] = P.dinv[z];
    GA.Hh[z] = hh[z]; GA.Hl[z] = hl[z];
  }

  // ---- GCN layer 1: XW (bf16-hi out) -> aggregate ----
  for (int z = 0; z < 2; ++z) {
    MA.Ah[z] = hh[z]; MA.Al[z] = hl[z];
    MA.Bh[z] = wg1h[z]; MA.Bl[z] = wg1l[z];
    MA.Ch[z] = xwh[z];
  }
  k_mm<false, false, 2, false, false><<<dim3(63, FF / 128, 2), 256, 0, stream>>>(MA, NN, FF, FF);
  GA.bias[0] = bg1; GA.bias[1] = bd1;
  k_aggregate<<<dim3(8000, 1, 2), 256, 0, stream>>>(GA);

  // ---- GCN layer 2 ----
  for (int z = 0; z < 2; ++z) { MA.Bh[z] = wg2h[z]; MA.Bl[z] = wg2l[z]; }
  k_mm<false, false, 2, false, false><<<dim3(63, FF / 128, 2), 256, 0, stream>>>(MA, NN, FF, FF);
  GA.bias[0] = bg2; GA.bias[1] = bd2;
  k_aggregate<<<dim3(8000, 1, 2), 256, 0, stream>>>(GA);

  // ---- MLP1: 512 -> 256, hi+lo planes out ----
  MA.bias[0] = lx1_b; MA.bias[1] = ly1_b;
  for (int z = 0; z < 2; ++z) {
    MA.Bh[z] = wl1h[z]; MA.Bl[z] = wl1l[z];
    MA.Ch[z] = p1h[z]; MA.Cl[z] = p1l[z];
  }
  k_mm<true, true, 1, false, false><<<dim3(63, 2, 2), 256, 0, stream>>>(MA, NN, 256, FF);

  // ---- MLP2: 256 -> 128 ----
  MA.bias[0] = lx2_b; MA.bias[1] = ly2_b;
  for (int z = 0; z < 2; ++z) {
    MA.Ah[z] = p1h[z]; MA.Al[z] = p1l[z];
    MA.Bh[z] = wl2h[z]; MA.Bl[z] = wl2l[z];
    MA.Ch[z] = p2h[z]; MA.Cl[z] = p2l[z];
  }
  k_mm<true, true, 1, false, false><<<dim3(63, 1, 2), 256, 0, stream>>>(MA, NN, 128, 256);

  // ---- MLP3: 128 -> 64 (N-guard) ----
  MA.bias[0] = lx3_b; MA.bias[1] = ly3_b;
  for (int z = 0; z < 2; ++z) {
    MA.Ah[z] = p2h[z]; MA.Al[z] = p2l[z];
    MA.Bh[z] = wl3h[z]; MA.Bl[z] = wl3l[z];
    MA.Ch[z] = fh[z]; MA.Cl[z] = fl[z];
  }
  k_mm<true, true, 1, true, false><<<dim3(63, 1, 2), 256, 0, stream>>>(MA, NN, 64, 128);

  // ---- scores = x @ y^T (nontemporal 256 MB write) ----
  MMArgs SC;
  SC.Ah[0] = fh[0]; SC.Al[0] = fl[0];
  SC.Bh[0] = fh[1]; SC.Bl[0] = fl[1];
  SC.Ah[1] = SC.Ah[0]; SC.Al[1] = SC.Al[0]; SC.Bh[1] = SC.Bh[0]; SC.Bl[1] = SC.Bl[0];
  SC.bias[0] = nullptr; SC.bias[1] = nullptr;
  SC.C[0] = out; SC.C[1] = out;
  SC.Ch[0] = SC.Ch[1] = nullptr; SC.Cl[0] = SC.Cl[1] = nullptr;
  k_mm<false, false, 0, true, true><<<dim3(63, 63, 1), 256, 0, stream>>>(SC, NN, NN, 64);
}

// Round 13
// 376.121 us; speedup vs baseline: 1.2451x; 1.0470x over previous
//
#include <hip/hip_runtime.h>

typedef unsigned short u16;
typedef unsigned int u32;
typedef __attribute__((ext_vector_type(8))) short bf16x8;
typedef __attribute__((ext_vector_type(4))) float f32x4;
typedef __attribute__((ext_vector_type(4))) unsigned short u16x4;
typedef __attribute__((ext_vector_type(2))) unsigned short u16x2;

static const int NN = 8000;    // nodes per graph (M == D)
static const int NE = 256000;  // edges per graph
static const int FF = 512;     // feature dim
static const int MP = 8064;    // 63 * 128 padded rows

__device__ __forceinline__ u16 f2bf(float x) {
  union { float f; u32 u; } a; a.f = x;
  u32 r = a.u + 0x7FFF + ((a.u >> 16) & 1);  // RNE
  return (u16)(r >> 16);
}
__device__ __forceinline__ float bf2f(u16 b) {
  union { float f; u32 u; } a; a.u = ((u32)b) << 16;
  return a.f;
}

__device__ __forceinline__ void gload_lds16(const void* g, void* l) {
  __builtin_amdgcn_global_load_lds(
      (const __attribute__((address_space(1))) unsigned int*)g,
      (__attribute__((address_space(3))) unsigned int*)l, 16, 0, 0);
}

// ---------------- arg structs (blockIdx.z = graph where applicable) --------

struct WTAll {
  const float* W[10];
  u16* Th[10];
  u16* Tl[10];
  int K[10], N[10];
  int toff[11];
};

// fused preprocessing: act-split | edge-weight gather | weight splits
struct PreFused {
  const float* x[2];
  u16* ph[2];
  u16* pl[2];
  const float* data[2];
  const int* ei[2];
  float* wbuf[2];
  float* deg[2];   // zeroed by memset; accumulates sum(w) only
  int* cnt[2];     // zeroed by memset
  WTAll wt;
};

struct PreArgs {
  const int* ei[2];
  float* wbuf[2];
  float* deg[2];
  int* cnt[2];
  float* dinv[2];
  int* colptr[2];
  int2* edata[2];  // packed (src, norm-bits)
};

struct MMArgs {
  const u16* Ah[2]; const u16* Al[2];
  const u16* Bh[2]; const u16* Bl[2];
  const float* bias[2];
  float* C[2];             // fp32 output (OUTMODE 0)
  u16* Ch[2]; u16* Cl[2];  // plane outputs (OUTMODE 1 = hi+lo, 2 = hi only)
};

struct AggArgs {
  const u16* XWh[2];       // bf16-hi XW planes [MP][FF]
  const int* colptr[2];
  const int2* edata[2];
  const float* dinv[2];
  const float* bias[2];
  u16* Hh[2];
  u16* Hl[2];
};

// ---------------- fused preprocessing ----------------
// block ranges: [0,sb) act-split | [sb,sb+eb) edge weights | rest: W splits.

__global__ __launch_bounds__(256) void k_pre(PreFused a, int sb, int eb, int wthalf,
                                             int tot_in, int tot_pad, int E, int n) {
  int z = blockIdx.z;
  int b = blockIdx.x;
  int tid = threadIdx.x;
  if (b < sb) {
    int i = (b * 256 + tid) * 4;
    if (i >= tot_pad) return;
    float4 v = (i < tot_in) ? *(const float4*)&a.x[z][i] : make_float4(0.f, 0.f, 0.f, 0.f);
    u16x4 h, l;
#pragma unroll
    for (int e = 0; e < 4; ++e) {
      float x = (&v.x)[e];
      u16 hh = f2bf(x);
      h[e] = hh;
      l[e] = f2bf(x - bf2f(hh));
    }
    *(u16x4*)&a.ph[z][i] = h;
    *(u16x4*)&a.pl[z][i] = l;
  } else if (b < sb + eb) {
    int e = (b - sb) * 256 + tid;
    if (e >= E) return;
    const int* ei = a.ei[z];
    int r = ei[e];
    int c = ei[E + e];
    float w = fmaxf(a.data[z][(size_t)r * n + c], 0.0f);
    a.wbuf[z][e] = w;
    atomicAdd(&a.deg[z][c], w);
    atomicAdd(&a.cnt[z][c], 1);
  } else {
    int bid = (b - sb - eb) + z * wthalf;
    int m = 0;
    while (bid >= a.wt.toff[m + 1]) ++m;
    int local = bid - a.wt.toff[m];
    int K = a.wt.K[m], N = a.wt.N[m];
    int ntn = N >> 5;
    int n0 = (local % ntn) * 32, k0 = (local / ntn) * 32;
    const float* W = a.wt.W[m];
    u16* Th = a.wt.Th[m];
    u16* Tl = a.wt.Tl[m];
    __shared__ float tile[32][33];
    int tx = tid & 31, ty = tid >> 5;
#pragma unroll
    for (int r = 0; r < 32; r += 8)
      tile[r + ty][tx] = W[(size_t)(k0 + r + ty) * N + n0 + tx];
    __syncthreads();
#pragma unroll
    for (int r = 0; r < 32; r += 8) {
      float v = tile[tx][r + ty];
      int nn = n0 + r + ty, k = k0 + tx;
      u16 h = f2bf(v);
      Th[(size_t)nn * K + k] = h;
      Tl[(size_t)nn * K + k] = f2bf(v - bf2f(h));
    }
  }
}

// one block per z: dinv = rsqrt(1 + sum_w) + exclusive scan of cnt; zero cnt
__global__ __launch_bounds__(256) void k_scan_dinv(PreArgs p, int n) {
  int z = blockIdx.z;
  const int* cnt = p.cnt[z];
  int* colptr = p.colptr[z];
  int* cntz = p.cnt[z];
  __shared__ int part[256];
  int t = threadIdx.x;
  const int CH = 32;
  int base = t * CH;
  for (int i = 0; i < CH; ++i) {
    int idx = base + i;
    if (idx < n) p.dinv[z][idx] = 1.0f / sqrtf(1.0f + p.deg[z][idx]);
  }
  int local[CH];
  int s = 0;
  for (int i = 0; i < CH; ++i) {
    int idx = base + i;
    int v = (idx < n) ? cnt[idx] : 0;
    local[i] = s;
    s += v;
  }
  part[t] = s;
  __syncthreads();
  for (int o = 1; o < 256; o <<= 1) {
    int v = (t >= o) ? part[t - o] : 0;
    __syncthreads();
    part[t] += v;
    __syncthreads();
  }
  int pre = (t == 0) ? 0 : part[t - 1];
  for (int i = 0; i < CH; ++i) {
    int idx = base + i;
    if (idx < n) { colptr[idx] = pre + local[i]; cntz[idx] = 0; }
  }
  if (t == 255) colptr[n] = part[255];
}

__global__ __launch_bounds__(256) void k_scatter(PreArgs p, int E) {
  int z = blockIdx.z;
  int e = blockIdx.x * 256 + threadIdx.x;
  if (e >= E) return;
  const int* ei = p.ei[z];
  int r = ei[e], c = ei[E + e];
  int pos = p.colptr[z][c] + atomicAdd(&p.cnt[z][c], 1);
  int2 sn;
  sn.x = r;
  sn.y = __float_as_int(p.dinv[z][r] * p.wbuf[z][e] * p.dinv[z][c]);
  p.edata[z][pos] = sn;
}

// ---------------- bf16x3 MFMA GEMM ----------------
// OUTMODE: 0 = fp32 C, 1 = bf16 hi+lo planes, 2 = bf16 hi-only plane.

template <bool BIAS, bool RELU, int OUTMODE, bool GUARD, bool NT>
__global__ __launch_bounds__(256) void k_mm(MMArgs a, int M, int N, int K) {
  __shared__ __align__(16) char smem[67584];  // staging 64KB | f32 tile 128*132*4
  u16 (*lds)[4][4096] = (u16(*)[4][4096])smem;
  float* ct = (float*)smem;

  int z = blockIdx.z;
  int tid = threadIdx.x;
  int wv = tid >> 6, ln = tid & 63;
  int l15 = ln & 15, l4 = ln >> 4;
  int m0 = blockIdx.x * 128, n0 = blockIdx.y * 128;
  int wm = (wv & 1) * 64, wn = (wv >> 1) * 64;
  const u16* gb = (wv == 0) ? a.Ah[z] : (wv == 1) ? a.Al[z] : (wv == 2) ? a.Bh[z] : a.Bl[z];
  int row0 = (wv < 2) ? m0 : n0;

  f32x4 acc[4][4];
  f32x4 zz = {0.f, 0.f, 0.f, 0.f};
#pragma unroll
  for (int i = 0; i < 4; ++i)
#pragma unroll
    for (int j = 0; j < 4; ++j) acc[i][j] = zz;

  auto stage = [&](int d, int k0) {
#pragma unroll
    for (int it = 0; it < 8; ++it) {
      int slot = it * 64 + ln;
      int r = slot >> 2, c = slot & 3;
      int gc = c ^ ((r >> 2) & 3);
      gload_lds16(gb + ((size_t)(row0 + r) * K + k0 + gc * 8),
                  &lds[d][wv][it * 512]);
    }
  };

  auto compute = [&](int d) {
    bf16x8 ah[4], al[4], bh[4], bl[4];
#pragma unroll
    for (int i = 0; i < 4; ++i) {
      int r = wm + i * 16 + l15;
      int off = r * 32 + ((l4 ^ ((r >> 2) & 3)) << 3);
      ah[i] = *(const bf16x8*)&lds[d][0][off];
      al[i] = *(const bf16x8*)&lds[d][1][off];
    }
#pragma unroll
    for (int j = 0; j < 4; ++j) {
      int r = wn + j * 16 + l15;
      int off = r * 32 + ((l4 ^ ((r >> 2) & 3)) << 3);
      bh[j] = *(const bf16x8*)&lds[d][2][off];
      bl[j] = *(const bf16x8*)&lds[d][3][off];
    }
#pragma unroll
    for (int i = 0; i < 4; ++i)
#pragma unroll
      for (int j = 0; j < 4; ++j) {
        acc[i][j] = __builtin_amdgcn_mfma_f32_16x16x32_bf16(ah[i], bh[j], acc[i][j], 0, 0, 0);
        acc[i][j] = __builtin_amdgcn_mfma_f32_16x16x32_bf16(al[i], bh[j], acc[i][j], 0, 0, 0);
        acc[i][j] = __builtin_amdgcn_mfma_f32_16x16x32_bf16(ah[i], bl[j], acc[i][j], 0, 0, 0);
      }
  };

  stage(0, 0);
  __syncthreads();
  int nk = K >> 5;
  for (int t = 0; t < nk; ++t) {
    int cur = t & 1;
    if (t + 1 < nk) stage(cur ^ 1, (t + 1) << 5);
    compute(cur);
    __syncthreads();
  }

  // ---- epilogue: acc (D layout col=lane&15, row=4*(lane>>4)+reg) -> LDS ----
#pragma unroll
  for (int i = 0; i < 4; ++i)
#pragma unroll
    for (int rr = 0; rr < 4; ++rr) {
      int row = wm + i * 16 + l4 * 4 + rr;
#pragma unroll
      for (int j = 0; j < 4; ++j) {
        int col = wn + l15 + j * 16;
        ct[row * 132 + col] = acc[i][j][rr];
      }
    }
  __syncthreads();

  int tcol = (tid & 31) * 4;
  int trow = tid >> 5;
#pragma unroll
  for (int p = 0; p < 16; ++p) {
    int row = p * 8 + trow;
    int m = m0 + row;
    int n = n0 + tcol;
    if (GUARD && n >= N) continue;
    f32x4 v = *(f32x4*)&ct[row * 132 + tcol];
    float o[4];
#pragma unroll
    for (int e = 0; e < 4; ++e) {
      float x = v[e];
      if (BIAS) x += a.bias[z][n + e];
      if (RELU) x = fmaxf(x, 0.0f);
      o[e] = x;
    }
    if (OUTMODE >= 1) {
      u16x4 hh, ll;
      if (m < M) {
#pragma unroll
        for (int e = 0; e < 4; ++e) {
          u16 h = f2bf(o[e]);
          hh[e] = h;
          if (OUTMODE == 1) ll[e] = f2bf(o[e] - bf2f(h));
        }
      } else {
#pragma unroll
        for (int e = 0; e < 4; ++e) { hh[e] = 0; ll[e] = 0; }
      }
      *(u16x4*)&a.Ch[z][(size_t)m * N + n] = hh;
      if (OUTMODE == 1) *(u16x4*)&a.Cl[z][(size_t)m * N + n] = ll;
    } else {
      if (m < M) {
        f32x4 o4 = {o[0], o[1], o[2], o[3]};
        if (NT)
          __builtin_nontemporal_store(o4, (f32x4*)&a.C[z][(size_t)m * N + n]);
        else
          *(f32x4*)&a.C[z][(size_t)m * N + n] = o4;
      }
    }
  }
}

// ---------------- sparse aggregation: static, bf16 gathers, L2 slabs -------
// XW gathered as bf16-hi (2B/elem): chunk slab = 8000*128*2B = 2MB; both
// graphs' slabs (4MB) fit one XCD L2 under chunk = bid&3. One wave = one
// (node, 128-elem chunk); u16x2/lane (256B/wave/edge contiguous). LDS edge
// staging (one coalesced load per 64 edges), 4 independent accumulator
// pairs, no atomics; static single-writer mapping (G16-safe). fp32 accum.

__global__ __launch_bounds__(256) void k_aggregate(AggArgs a) {
  __shared__ int2 ebuf[4][64];
  int z = blockIdx.z;
  int bid = blockIdx.x;               // 0..7999
  int wv = threadIdx.x >> 6, ln = threadIdx.x & 63;
  int chunk = bid & 3;                // 4 chunks x 128 elems (2MB slab)
  int c = (bid >> 2) * 4 + wv;        // node 0..7999
  int fo = chunk * 128 + ln * 2;
  const u16* XWh = a.XWh[z];
  const int2* ed = a.edata[z];
  int e0 = a.colptr[z][c], e1 = a.colptr[z][c + 1];
  float di = a.dinv[z][c];
  float sl = di * di;

  u16x2 sh = *(const u16x2*)&XWh[(size_t)c * FF + fo];
  float x0 = bf2f(sh[0]) * sl, y0 = bf2f(sh[1]) * sl;
  float x1 = 0.f, y1 = 0.f, x2 = 0.f, y2 = 0.f, x3 = 0.f, y3 = 0.f;

  for (int base = e0; base < e1; base += 64) {
    if (base + ln < e1) ebuf[wv][ln] = ed[base + ln];
    int rem = e1 - base;
    int ne = rem < 64 ? rem : 64;
    int j = 0;
    for (; j + 4 <= ne; j += 4) {
      int2 d0 = ebuf[wv][j], d1 = ebuf[wv][j + 1];
      int2 d2 = ebuf[wv][j + 2], d3 = ebuf[wv][j + 3];
      u16x2 q0 = *(const u16x2*)&XWh[(size_t)d0.x * FF + fo];
      u16x2 q1 = *(const u16x2*)&XWh[(size_t)d1.x * FF + fo];
      u16x2 q2 = *(const u16x2*)&XWh[(size_t)d2.x * FF + fo];
      u16x2 q3 = *(const u16x2*)&XWh[(size_t)d3.x * FF + fo];
      float w0 = __int_as_float(d0.y), w1 = __int_as_float(d1.y);
      float w2 = __int_as_float(d2.y), w3 = __int_as_float(d3.y);
      x0 = fmaf(w0, bf2f(q0[0]), x0); y0 = fmaf(w0, bf2f(q0[1]), y0);
      x1 = fmaf(w1, bf2f(q1[0]), x1); y1 = fmaf(w1, bf2f(q1[1]), y1);
      x2 = fmaf(w2, bf2f(q2[0]), x2); y2 = fmaf(w2, bf2f(q2[1]), y2);
      x3 = fmaf(w3, bf2f(q3[0]), x3); y3 = fmaf(w3, bf2f(q3[1]), y3);
    }
    for (; j < ne; ++j) {
      int2 d0 = ebuf[wv][j];
      u16x2 q0 = *(const u16x2*)&XWh[(size_t)d0.x * FF + fo];
      float w0 = __int_as_float(d0.y);
      x0 = fmaf(w0, bf2f(q0[0]), x0); y0 = fmaf(w0, bf2f(q0[1]), y0);
    }
  }

  float2 b2 = *(const float2*)&a.bias[z][fo];
  float ox = fmaxf((x0 + x1) + (x2 + x3) + b2.x, 0.0f);
  float oy = fmaxf((y0 + y1) + (y2 + y3) + b2.y, 0.0f);
  u16 hx = f2bf(ox), hy = f2bf(oy);
  u16x2 hh = {hx, hy};
  u16x2 ll = {f2bf(ox - bf2f(hx)), f2bf(oy - bf2f(hy))};
  *(u16x2*)&a.Hh[z][(size_t)c * FF + fo] = hh;
  *(u16x2*)&a.Hl[z][(size_t)c * FF + fo] = ll;
}

// ---------------- host orchestration ----------------

extern "C" void kernel_launch(void* const* d_in, const int* in_sizes, int n_in,
                              void* d_out, int out_size, void* d_ws, size_t ws_size,
                              hipStream_t stream) {
  const float* x_m    = (const float*)d_in[0];
  const float* x_d    = (const float*)d_in[1];
  const float* data_m = (const float*)d_in[2];
  const float* data_d = (const float*)d_in[3];
  const int*   ei_m   = (const int*)d_in[4];
  const int*   ei_d   = (const int*)d_in[5];
  const float* Wg1 = (const float*)d_in[6];
  const float* bg1 = (const float*)d_in[7];
  const float* Wg2 = (const float*)d_in[8];
  const float* bg2 = (const float*)d_in[9];
  const float* Wd1 = (const float*)d_in[10];
  const float* bd1 = (const float*)d_in[11];
  const float* Wd2 = (const float*)d_in[12];
  const float* bd2 = (const float*)d_in[13];
  const float* lx1_w = (const float*)d_in[14];
  const float* lx1_b = (const float*)d_in[15];
  const float* lx2_w = (const float*)d_in[16];
  const float* lx2_b = (const float*)d_in[17];
  const float* lx3_w = (const float*)d_in[18];
  const float* lx3_b = (const float*)d_in[19];
  const float* ly1_w = (const float*)d_in[20];
  const float* ly1_b = (const float*)d_in[21];
  const float* ly2_w = (const float*)d_in[22];
  const float* ly2_b = (const float*)d_in[23];
  const float* ly3_w = (const float*)d_in[24];
  const float* ly3_b = (const float*)d_in[25];
  float* out = (float*)d_out;

  char* base = (char*)d_ws;
  size_t off = 0;
  auto alloc = [&](size_t bytes) -> char* {
    char* p = base + off;
    off += (bytes + 255) & ~(size_t)255;
    return p;
  };
  u16* hh[2], *hl[2];
  for (int z = 0; z < 2; ++z) {
    hh[z] = (u16*)alloc((size_t)MP * FF * 2);
    hl[z] = (u16*)alloc((size_t)MP * FF * 2);
  }
  u16* xwh[2];  // bf16-hi XW (GCN GEMM output / aggregation input)
  for (int z = 0; z < 2; ++z) xwh[z] = (u16*)alloc((size_t)MP * FF * 2);
  u16* p1h[2], *p1l[2], *p2h[2], *p2l[2], *fh[2], *fl[2];
  for (int z = 0; z < 2; ++z) {
    p1h[z] = (u16*)alloc((size_t)MP * 256 * 2);
    p1l[z] = (u16*)alloc((size_t)MP * 256 * 2);
    p2h[z] = (u16*)alloc((size_t)MP * 128 * 2);
    p2l[z] = (u16*)alloc((size_t)MP * 128 * 2);
    fh[z]  = (u16*)alloc((size_t)MP * 64 * 2);
    fl[z]  = (u16*)alloc((size_t)MP * 64 * 2);
  }
  u16 *wg1h[2], *wg1l[2], *wg2h[2], *wg2l[2], *wl1h[2], *wl1l[2],
      *wl2h[2], *wl2l[2], *wl3h[2], *wl3l[2];
  for (int z = 0; z < 2; ++z) {
    wg1h[z] = (u16*)alloc((size_t)512 * 512 * 2);
    wg1l[z] = (u16*)alloc((size_t)512 * 512 * 2);
    wg2h[z] = (u16*)alloc((size_t)512 * 512 * 2);
    wg2l[z] = (u16*)alloc((size_t)512 * 512 * 2);
    wl1h[z] = (u16*)alloc((size_t)512 * 256 * 2);
    wl1l[z] = (u16*)alloc((size_t)512 * 256 * 2);
    wl2h[z] = (u16*)alloc((size_t)256 * 128 * 2);
    wl2l[z] = (u16*)alloc((size_t)256 * 128 * 2);
    wl3h[z] = (u16*)alloc((size_t)128 * 64 * 2);
    wl3l[z] = (u16*)alloc((size_t)128 * 64 * 2);
  }
  // deg/cnt contiguous for one memset: [deg0|cnt0|deg1|cnt1]
  float* degcnt = (float*)alloc((size_t)4 * NN * 4);
  PreArgs P;
  PreFused PF;
  PF.x[0] = x_m; PF.x[1] = x_d;
  PF.data[0] = data_m; PF.data[1] = data_d;
  for (int z = 0; z < 2; ++z) {
    PF.ph[z] = hh[z]; PF.pl[z] = hl[z];
    PF.ei[z] = z ? ei_d : ei_m;
    PF.wbuf[z] = (float*)alloc((size_t)NE * 4);
    PF.deg[z] = degcnt + (size_t)2 * NN * z;
    PF.cnt[z] = (int*)(degcnt + (size_t)2 * NN * z + NN);
    P.ei[z] = PF.ei[z];
    P.wbuf[z] = PF.wbuf[z];
    P.deg[z] = PF.deg[z];
    P.cnt[z] = PF.cnt[z];
    P.edata[z]  = (int2*)alloc((size_t)NE * 8);
    P.dinv[z]   = (float*)alloc((size_t)NN * 4);
    P.colptr[z] = (int*)alloc((size_t)(NN + 1) * 4);
  }

  // ---- weight split table ----
  const float* Wsrc[10] = {Wg1, Wg2, lx1_w, lx2_w, lx3_w, Wd1, Wd2, ly1_w, ly2_w, ly3_w};
  u16* Thd[10] = {wg1h[0], wg2h[0], wl1h[0], wl2h[0], wl3h[0],
                  wg1h[1], wg2h[1], wl1h[1], wl2h[1], wl3h[1]};
  u16* Tld[10] = {wg1l[0], wg2l[0], wl1l[0], wl2l[0], wl3l[0],
                  wg1l[1], wg2l[1], wl1l[1], wl2l[1], wl3l[1]};
  int Ks[10] = {512, 512, 512, 256, 128, 512, 512, 512, 256, 128};
  int Ns[10] = {512, 512, 256, 128, 64, 512, 512, 256, 128, 64};
  int acc_t = 0;
  for (int m = 0; m < 10; ++m) {
    PF.wt.W[m] = Wsrc[m]; PF.wt.Th[m] = Thd[m]; PF.wt.Tl[m] = Tld[m];
    PF.wt.K[m] = Ks[m]; PF.wt.N[m] = Ns[m];
    PF.wt.toff[m] = acc_t;
    acc_t += (Ns[m] / 32) * (Ks[m] / 32);
  }
  PF.wt.toff[10] = acc_t;       // 1360
  int wthalf = acc_t / 2;       // 680

  int sb = (MP * FF / 4 + 255) / 256;  // 4032
  int eb = (NE + 255) / 256;           // 1000

  // ---- preprocessing: memset -> fused pre -> scan -> scatter ----
  hipMemsetAsync(degcnt, 0, (size_t)4 * NN * 4, stream);
  k_pre<<<dim3(sb + eb + wthalf, 1, 2), 256, 0, stream>>>(
      PF, sb, eb, wthalf, NN * FF, MP * FF, NE, NN);
  k_scan_dinv<<<dim3(1, 1, 2), 256, 0, stream>>>(P, NN);
  k_scatter<<<dim3(eb, 1, 2), 256, 0, stream>>>(P, NE);

  MMArgs MA;
  AggArgs GA;
  for (int z = 0; z < 2; ++z) {
    MA.bias[z] = nullptr; MA.C[z] = nullptr; MA.Ch[z] = nullptr; MA.Cl[z] = nullptr;
    GA.XWh[z] = xwh[z];
    GA.colptr[z] = P.colptr[z];
    GA.edata[z] = P.edata[z];
    GA.dinv[z] = P.dinv[z];
    GA.Hh[z] = hh[z]; GA.Hl[z] = hl[z];
  }

  // ---- GCN layer 1: XW (bf16-hi out) -> aggregate ----
  for (int z = 0; z < 2; ++z) {
    MA.Ah[z] = hh[z]; MA.Al[z] = hl[z];
    MA.Bh[z] = wg1h[z]; MA.Bl[z] = wg1l[z];
    MA.Ch[z] = xwh[z];
  }
  k_mm<false, false, 2, false, false><<<dim3(63, FF / 128, 2), 256, 0, stream>>>(MA, NN, FF, FF);
  GA.bias[0] = bg1; GA.bias[1] = bd1;
  k_aggregate<<<dim3(8000, 1, 2), 256, 0, stream>>>(GA);

  // ---- GCN layer 2 ----
  for (int z = 0; z < 2; ++z) { MA.Bh[z] = wg2h[z]; MA.Bl[z] = wg2l[z]; }
  k_mm<false, false, 2, false, false><<<dim3(63, FF / 128, 2), 256, 0, stream>>>(MA, NN, FF, FF);
  GA.bias[0] = bg2; GA.bias[1] = bd2;
  k_aggregate<<<dim3(8000, 1, 2), 256, 0, stream>>>(GA);

  // ---- MLP1: 512 -> 256, hi+lo planes out ----
  MA.bias[0] = lx1_b; MA.bias[1] = ly1_b;
  for (int z = 0; z < 2; ++z) {
    MA.Bh[z] = wl1h[z]; MA.Bl[z] = wl1l[z];
    MA.Ch[z] = p1h[z]; MA.Cl[z] = p1l[z];
  }
  k_mm<true, true, 1, false, false><<<dim3(63, 2, 2), 256, 0, stream>>>(MA, NN, 256, FF);

  // ---- MLP2: 256 -> 128 ----
  MA.bias[0] = lx2_b; MA.bias[1] = ly2_b;
  for (int z = 0; z < 2; ++z) {
    MA.Ah[z] = p1h[z]; MA.Al[z] = p1l[z];
    MA.Bh[z] = wl2h[z]; MA.Bl[z] = wl2l[z];
    MA.Ch[z] = p2h[z]; MA.Cl[z] = p2l[z];
  }
  k_mm<true, true, 1, false, false><<<dim3(63, 1, 2), 256, 0, stream>>>(MA, NN, 128, 256);

  // ---- MLP3: 128 -> 64 (N-guard) ----
  MA.bias[0] = lx3_b; MA.bias[1] = ly3_b;
  for (int z = 0; z < 2; ++z) {
    MA.Ah[z] = p2h[z]; MA.Al[z] = p2l[z];
    MA.Bh[z] = wl3h[z]; MA.Bl[z] = wl3l[z];
    MA.Ch[z] = fh[z]; MA.Cl[z] = fl[z];
  }
  k_mm<true, true, 1, true, false><<<dim3(63, 1, 2), 256, 0, stream>>>(MA, NN, 64, 128);

  // ---- scores = x @ y^T (nontemporal 256 MB write) ----
  MMArgs SC;
  SC.Ah[0] = fh[0]; SC.Al[0] = fl[0];
  SC.Bh[0] = fh[1]; SC.Bl[0] = fl[1];
  SC.Ah[1] = SC.Ah[0]; SC.Al[1] = SC.Al[0]; SC.Bh[1] = SC.Bh[0]; SC.Bl[1] = SC.Bl[0];
  SC.bias[0] = nullptr; SC.bias[1] = nullptr;
  SC.C[0] = out; SC.C[1] = out;
  SC.Ch[0] = SC.Ch[1] = nullptr; SC.Cl[0] = SC.Cl[1] = nullptr;
  k_mm<false, false, 0, true, true><<<dim3(63, 63, 1), 256, 0, stream>>>(SC, NN, NN, 64);
}

// Round 14
// 366.280 us; speedup vs baseline: 1.2785x; 1.0269x over previous
//
#include <hip/hip_runtime.h>

typedef unsigned short u16;
typedef unsigned int u32;
typedef __attribute__((ext_vector_type(8))) short bf16x8;
typedef __attribute__((ext_vector_type(4))) float f32x4;
typedef __attribute__((ext_vector_type(4))) unsigned short u16x4;
typedef __attribute__((ext_vector_type(2))) unsigned short u16x2;

static const int NN = 8000;    // nodes per graph (M == D)
static const int NE = 256000;  // edges per graph
static const int FF = 512;     // feature dim
static const int MP = 8064;    // 63 * 128 padded rows

__device__ __forceinline__ u16 f2bf(float x) {
  union { float f; u32 u; } a; a.f = x;
  u32 r = a.u + 0x7FFF + ((a.u >> 16) & 1);  // RNE
  return (u16)(r >> 16);
}
__device__ __forceinline__ float bf2f(u16 b) {
  union { float f; u32 u; } a; a.u = ((u32)b) << 16;
  return a.f;
}

__device__ __forceinline__ void gload_lds16(const void* g, void* l) {
  __builtin_amdgcn_global_load_lds(
      (const __attribute__((address_space(1))) unsigned int*)g,
      (__attribute__((address_space(3))) unsigned int*)l, 16, 0, 0);
}

// ---------------- arg structs (blockIdx.z = graph where applicable) --------

struct WTAll {
  const float* W[10];
  u16* Th[10];
  u16* Tl[10];
  int K[10], N[10];
  int toff[11];
};

// fused preprocessing: act-split | edge-weight gather | weight splits
struct PreFused {
  const float* x[2];
  u16* ph[2];
  u16* pl[2];
  const float* data[2];
  const int* ei[2];
  float* wbuf[2];
  float* deg[2];   // zeroed by memset; accumulates sum(w) only
  int* cnt[2];     // zeroed by memset
  WTAll wt;
};

struct PreArgs {
  const int* ei[2];
  float* wbuf[2];
  float* deg[2];
  int* cnt[2];
  float* dinv[2];
  int* colptr[2];
  int2* edata[2];  // packed (src byte-offset, norm-bits)
};

struct MMArgs {
  const u16* Ah[2]; const u16* Al[2];
  const u16* Bh[2]; const u16* Bl[2];
  const float* bias[2];
  float* C[2];             // fp32 output (OUTMODE 0)
  u16* Ch[2]; u16* Cl[2];  // plane outputs (OUTMODE 1 = hi+lo, 2 = hi only)
};

struct AggArgs {
  const u16* XWh[2];       // bf16-hi XW planes [MP][FF]
  const int* colptr[2];
  const int2* edata[2];
  const float* dinv[2];
  const float* bias[2];
  u16* Hh[2];
  u16* Hl[2];
};

// ---------------- fused preprocessing ----------------
// block ranges: [0,sb) act-split | [sb,sb+eb) edge weights | rest: W splits.

__global__ __launch_bounds__(256) void k_pre(PreFused a, int sb, int eb, int wthalf,
                                             int tot_in, int tot_pad, int E, int n) {
  int z = blockIdx.z;
  int b = blockIdx.x;
  int tid = threadIdx.x;
  if (b < sb) {
    int i = (b * 256 + tid) * 4;
    if (i >= tot_pad) return;
    float4 v = (i < tot_in) ? *(const float4*)&a.x[z][i] : make_float4(0.f, 0.f, 0.f, 0.f);
    u16x4 h, l;
#pragma unroll
    for (int e = 0; e < 4; ++e) {
      float x = (&v.x)[e];
      u16 hh = f2bf(x);
      h[e] = hh;
      l[e] = f2bf(x - bf2f(hh));
    }
    *(u16x4*)&a.ph[z][i] = h;
    *(u16x4*)&a.pl[z][i] = l;
  } else if (b < sb + eb) {
    int e = (b - sb) * 256 + tid;
    if (e >= E) return;
    const int* ei = a.ei[z];
    int r = ei[e];
    int c = ei[E + e];
    float w = fmaxf(a.data[z][(size_t)r * n + c], 0.0f);
    a.wbuf[z][e] = w;
    atomicAdd(&a.deg[z][c], w);
    atomicAdd(&a.cnt[z][c], 1);
  } else {
    int bid = (b - sb - eb) + z * wthalf;
    int m = 0;
    while (bid >= a.wt.toff[m + 1]) ++m;
    int local = bid - a.wt.toff[m];
    int K = a.wt.K[m], N = a.wt.N[m];
    int ntn = N >> 5;
    int n0 = (local % ntn) * 32, k0 = (local / ntn) * 32;
    const float* W = a.wt.W[m];
    u16* Th = a.wt.Th[m];
    u16* Tl = a.wt.Tl[m];
    __shared__ float tile[32][33];
    int tx = tid & 31, ty = tid >> 5;
#pragma unroll
    for (int r = 0; r < 32; r += 8)
      tile[r + ty][tx] = W[(size_t)(k0 + r + ty) * N + n0 + tx];
    __syncthreads();
#pragma unroll
    for (int r = 0; r < 32; r += 8) {
      float v = tile[tx][r + ty];
      int nn = n0 + r + ty, k = k0 + tx;
      u16 h = f2bf(v);
      Th[(size_t)nn * K + k] = h;
      Tl[(size_t)nn * K + k] = f2bf(v - bf2f(h));
    }
  }
}

// one block per z: dinv = rsqrt(1 + sum_w) + exclusive scan of cnt; zero cnt
__global__ __launch_bounds__(256) void k_scan_dinv(PreArgs p, int n) {
  int z = blockIdx.z;
  const int* cnt = p.cnt[z];
  int* colptr = p.colptr[z];
  int* cntz = p.cnt[z];
  __shared__ int part[256];
  int t = threadIdx.x;
  const int CH = 32;
  int base = t * CH;
  for (int i = 0; i < CH; ++i) {
    int idx = base + i;
    if (idx < n) p.dinv[z][idx] = 1.0f / sqrtf(1.0f + p.deg[z][idx]);
  }
  int local[CH];
  int s = 0;
  for (int i = 0; i < CH; ++i) {
    int idx = base + i;
    int v = (idx < n) ? cnt[idx] : 0;
    local[i] = s;
    s += v;
  }
  part[t] = s;
  __syncthreads();
  for (int o = 1; o < 256; o <<= 1) {
    int v = (t >= o) ? part[t - o] : 0;
    __syncthreads();
    part[t] += v;
    __syncthreads();
  }
  int pre = (t == 0) ? 0 : part[t - 1];
  for (int i = 0; i < CH; ++i) {
    int idx = base + i;
    if (idx < n) { colptr[idx] = pre + local[i]; cntz[idx] = 0; }
  }
  if (t == 255) colptr[n] = part[255];
}

__global__ __launch_bounds__(256) void k_scatter(PreArgs p, int E) {
  int z = blockIdx.z;
  int e = blockIdx.x * 256 + threadIdx.x;
  if (e >= E) return;
  const int* ei = p.ei[z];
  int r = ei[e], c = ei[E + e];
  int pos = p.colptr[z][c] + atomicAdd(&p.cnt[z][c], 1);
  int2 sn;
  sn.x = r << 10;  // pre-scaled byte offset: r * FF * 2
  sn.y = __float_as_int(p.dinv[z][r] * p.wbuf[z][e] * p.dinv[z][c]);
  p.edata[z][pos] = sn;
}

// ---------------- bf16x3 MFMA GEMM ----------------
// OUTMODE: 0 = fp32 C, 1 = bf16 hi+lo planes, 2 = bf16 hi-only plane.

template <bool BIAS, bool RELU, int OUTMODE, bool GUARD, bool NT>
__global__ __launch_bounds__(256) void k_mm(MMArgs a, int M, int N, int K) {
  __shared__ __align__(16) char smem[67584];  // staging 64KB | f32 tile 128*132*4
  u16 (*lds)[4][4096] = (u16(*)[4][4096])smem;
  float* ct = (float*)smem;

  int z = blockIdx.z;
  int tid = threadIdx.x;
  int wv = tid >> 6, ln = tid & 63;
  int l15 = ln & 15, l4 = ln >> 4;
  int m0 = blockIdx.x * 128, n0 = blockIdx.y * 128;
  int wm = (wv & 1) * 64, wn = (wv >> 1) * 64;
  const u16* gb = (wv == 0) ? a.Ah[z] : (wv == 1) ? a.Al[z] : (wv == 2) ? a.Bh[z] : a.Bl[z];
  int row0 = (wv < 2) ? m0 : n0;

  f32x4 acc[4][4];
  f32x4 zz = {0.f, 0.f, 0.f, 0.f};
#pragma unroll
  for (int i = 0; i < 4; ++i)
#pragma unroll
    for (int j = 0; j < 4; ++j) acc[i][j] = zz;

  auto stage = [&](int d, int k0) {
#pragma unroll
    for (int it = 0; it < 8; ++it) {
      int slot = it * 64 + ln;
      int r = slot >> 2, c = slot & 3;
      int gc = c ^ ((r >> 2) & 3);
      gload_lds16(gb + ((size_t)(row0 + r) * K + k0 + gc * 8),
                  &lds[d][wv][it * 512]);
    }
  };

  auto compute = [&](int d) {
    bf16x8 ah[4], al[4], bh[4], bl[4];
#pragma unroll
    for (int i = 0; i < 4; ++i) {
      int r = wm + i * 16 + l15;
      int off = r * 32 + ((l4 ^ ((r >> 2) & 3)) << 3);
      ah[i] = *(const bf16x8*)&lds[d][0][off];
      al[i] = *(const bf16x8*)&lds[d][1][off];
    }
#pragma unroll
    for (int j = 0; j < 4; ++j) {
      int r = wn + j * 16 + l15;
      int off = r * 32 + ((l4 ^ ((r >> 2) & 3)) << 3);
      bh[j] = *(const bf16x8*)&lds[d][2][off];
      bl[j] = *(const bf16x8*)&lds[d][3][off];
    }
#pragma unroll
    for (int i = 0; i < 4; ++i)
#pragma unroll
      for (int j = 0; j < 4; ++j) {
        acc[i][j] = __builtin_amdgcn_mfma_f32_16x16x32_bf16(ah[i], bh[j], acc[i][j], 0, 0, 0);
        acc[i][j] = __builtin_amdgcn_mfma_f32_16x16x32_bf16(al[i], bh[j], acc[i][j], 0, 0, 0);
        acc[i][j] = __builtin_amdgcn_mfma_f32_16x16x32_bf16(ah[i], bl[j], acc[i][j], 0, 0, 0);
      }
  };

  stage(0, 0);
  __syncthreads();
  int nk = K >> 5;
  for (int t = 0; t < nk; ++t) {
    int cur = t & 1;
    if (t + 1 < nk) stage(cur ^ 1, (t + 1) << 5);
    compute(cur);
    __syncthreads();
  }

  // ---- epilogue: acc (D layout col=lane&15, row=4*(lane>>4)+reg) -> LDS ----
#pragma unroll
  for (int i = 0; i < 4; ++i)
#pragma unroll
    for (int rr = 0; rr < 4; ++rr) {
      int row = wm + i * 16 + l4 * 4 + rr;
#pragma unroll
      for (int j = 0; j < 4; ++j) {
        int col = wn + l15 + j * 16;
        ct[row * 132 + col] = acc[i][j][rr];
      }
    }
  __syncthreads();

  int tcol = (tid & 31) * 4;
  int trow = tid >> 5;
#pragma unroll
  for (int p = 0; p < 16; ++p) {
    int row = p * 8 + trow;
    int m = m0 + row;
    int n = n0 + tcol;
    if (GUARD && n >= N) continue;
    f32x4 v = *(f32x4*)&ct[row * 132 + tcol];
    float o[4];
#pragma unroll
    for (int e = 0; e < 4; ++e) {
      float x = v[e];
      if (BIAS) x += a.bias[z][n + e];
      if (RELU) x = fmaxf(x, 0.0f);
      o[e] = x;
    }
    if (OUTMODE >= 1) {
      u16x4 hh, ll;
      if (m < M) {
#pragma unroll
        for (int e = 0; e < 4; ++e) {
          u16 h = f2bf(o[e]);
          hh[e] = h;
          if (OUTMODE == 1) ll[e] = f2bf(o[e] - bf2f(h));
        }
      } else {
#pragma unroll
        for (int e = 0; e < 4; ++e) { hh[e] = 0; ll[e] = 0; }
      }
      *(u16x4*)&a.Ch[z][(size_t)m * N + n] = hh;
      if (OUTMODE == 1) *(u16x4*)&a.Cl[z][(size_t)m * N + n] = ll;
    } else {
      if (m < M) {
        f32x4 o4 = {o[0], o[1], o[2], o[3]};
        if (NT)
          __builtin_nontemporal_store(o4, (f32x4*)&a.C[z][(size_t)m * N + n]);
        else
          *(f32x4*)&a.C[z][(size_t)m * N + n] = o4;
      }
    }
  }
}

// ---------------- sparse aggregation: static, bf16 gathers, L2 slabs -------
// XW gathered as bf16-hi (2B/elem): chunk slab = 8000*128*2B = 2MB; both
// graphs' slabs (4MB) fit one XCD L2 under chunk = bid&3. One wave = one
// (node, 128-elem chunk); u16x2/lane. edata.x is a PRE-SCALED row byte
// offset (src*1024) so the hot loop is one add per edge. LDS edge staging
// (one coalesced load per 64 edges), 8-way unroll with 8 independent
// accumulator pairs (deep load pipelining), no atomics; static
// single-writer mapping (G16-safe). fp32 accumulate.

__global__ __launch_bounds__(256) void k_aggregate(AggArgs a) {
  __shared__ int2 ebuf[4][64];
  int z = blockIdx.z;
  int bid = blockIdx.x;               // 0..7999
  int wv = threadIdx.x >> 6, ln = threadIdx.x & 63;
  int chunk = bid & 3;                // 4 chunks x 128 elems (2MB slab)
  int c = (bid >> 2) * 4 + wv;        // node 0..7999
  int fo = chunk * 128 + ln * 2;
  const char* XWb = (const char*)a.XWh[z];
  size_t fo2 = (size_t)fo * 2;        // byte offset within row
  const int2* ed = a.edata[z];
  int e0 = a.colptr[z][c], e1 = a.colptr[z][c + 1];
  float di = a.dinv[z][c];
  float sl = di * di;

  u16x2 sh = *(const u16x2*)(XWb + (size_t)c * 1024 + fo2);
  float xa[8], ya[8];
  xa[0] = bf2f(sh[0]) * sl; ya[0] = bf2f(sh[1]) * sl;
#pragma unroll
  for (int q = 1; q < 8; ++q) { xa[q] = 0.f; ya[q] = 0.f; }

  for (int base = e0; base < e1; base += 64) {
    if (base + ln < e1) ebuf[wv][ln] = ed[base + ln];
    int rem = e1 - base;
    int ne = rem < 64 ? rem : 64;
    int j = 0;
    for (; j + 8 <= ne; j += 8) {
      int2 d[8];
#pragma unroll
      for (int q = 0; q < 8; ++q) d[q] = ebuf[wv][j + q];
      u16x2 qv[8];
#pragma unroll
      for (int q = 0; q < 8; ++q)
        qv[q] = *(const u16x2*)(XWb + (size_t)(u32)d[q].x + fo2);
#pragma unroll
      for (int q = 0; q < 8; ++q) {
        float w = __int_as_float(d[q].y);
        xa[q] = fmaf(w, bf2f(qv[q][0]), xa[q]);
        ya[q] = fmaf(w, bf2f(qv[q][1]), ya[q]);
      }
    }
    for (; j < ne; ++j) {
      int2 d0 = ebuf[wv][j];
      u16x2 q0 = *(const u16x2*)(XWb + (size_t)(u32)d0.x + fo2);
      float w0 = __int_as_float(d0.y);
      xa[0] = fmaf(w0, bf2f(q0[0]), xa[0]); ya[0] = fmaf(w0, bf2f(q0[1]), ya[0]);
    }
  }

  float2 b2 = *(const float2*)&a.bias[z][fo];
  float ox = ((xa[0] + xa[1]) + (xa[2] + xa[3])) + ((xa[4] + xa[5]) + (xa[6] + xa[7]));
  float oy = ((ya[0] + ya[1]) + (ya[2] + ya[3])) + ((ya[4] + ya[5]) + (ya[6] + ya[7]));
  ox = fmaxf(ox + b2.x, 0.0f);
  oy = fmaxf(oy + b2.y, 0.0f);
  u16 hx = f2bf(ox), hy = f2bf(oy);
  u16x2 hh = {hx, hy};
  u16x2 ll = {f2bf(ox - bf2f(hx)), f2bf(oy - bf2f(hy))};
  *(u16x2*)&a.Hh[z][(size_t)c * FF + fo] = hh;
  *(u16x2*)&a.Hl[z][(size_t)c * FF + fo] = ll;
}

// ---------------- host orchestration ----------------

extern "C" void kernel_launch(void* const* d_in, const int* in_sizes, int n_in,
                              void* d_out, int out_size, void* d_ws, size_t ws_size,
                              hipStream_t stream) {
  const float* x_m    = (const float*)d_in[0];
  const float* x_d    = (const float*)d_in[1];
  const float* data_m = (const float*)d_in[2];
  const float* data_d = (const float*)d_in[3];
  const int*   ei_m   = (const int*)d_in[4];
  const int*   ei_d   = (const int*)d_in[5];
  const float* Wg1 = (const float*)d_in[6];
  const float* bg1 = (const float*)d_in[7];
  const float* Wg2 = (const float*)d_in[8];
  const float* bg2 = (const float*)d_in[9];
  const float* Wd1 = (const float*)d_in[10];
  const float* bd1 = (const float*)d_in[11];
  const float* Wd2 = (const float*)d_in[12];
  const float* bd2 = (const float*)d_in[13];
  const float* lx1_w = (const float*)d_in[14];
  const float* lx1_b = (const float*)d_in[15];
  const float* lx2_w = (const float*)d_in[16];
  const float* lx2_b = (const float*)d_in[17];
  const float* lx3_w = (const float*)d_in[18];
  const float* lx3_b = (const float*)d_in[19];
  const float* ly1_w = (const float*)d_in[20];
  const float* ly1_b = (const float*)d_in[21];
  const float* ly2_w = (const float*)d_in[22];
  const float* ly2_b = (const float*)d_in[23];
  const float* ly3_w = (const float*)d_in[24];
  const float* ly3_b = (const float*)d_in[25];
  float* out = (float*)d_out;

  char* base = (char*)d_ws;
  size_t off = 0;
  auto alloc = [&](size_t bytes) -> char* {
    char* p = base + off;
    off += (bytes + 255) & ~(size_t)255;
    return p;
  };
  u16* hh[2], *hl[2];
  for (int z = 0; z < 2; ++z) {
    hh[z] = (u16*)alloc((size_t)MP * FF * 2);
    hl[z] = (u16*)alloc((size_t)MP * FF * 2);
  }
  u16* xwh[2];  // bf16-hi XW (GCN GEMM output / aggregation input)
  for (int z = 0; z < 2; ++z) xwh[z] = (u16*)alloc((size_t)MP * FF * 2);
  u16* p1h[2], *p1l[2], *p2h[2], *p2l[2], *fh[2], *fl[2];
  for (int z = 0; z < 2; ++z) {
    p1h[z] = (u16*)alloc((size_t)MP * 256 * 2);
    p1l[z] = (u16*)alloc((size_t)MP * 256 * 2);
    p2h[z] = (u16*)alloc((size_t)MP * 128 * 2);
    p2l[z] = (u16*)alloc((size_t)MP * 128 * 2);
    fh[z]  = (u16*)alloc((size_t)MP * 64 * 2);
    fl[z]  = (u16*)alloc((size_t)MP * 64 * 2);
  }
  u16 *wg1h[2], *wg1l[2], *wg2h[2], *wg2l[2], *wl1h[2], *wl1l[2],
      *wl2h[2], *wl2l[2], *wl3h[2], *wl3l[2];
  for (int z = 0; z < 2; ++z) {
    wg1h[z] = (u16*)alloc((size_t)512 * 512 * 2);
    wg1l[z] = (u16*)alloc((size_t)512 * 512 * 2);
    wg2h[z] = (u16*)alloc((size_t)512 * 512 * 2);
    wg2l[z] = (u16*)alloc((size_t)512 * 512 * 2);
    wl1h[z] = (u16*)alloc((size_t)512 * 256 * 2);
    wl1l[z] = (u16*)alloc((size_t)512 * 256 * 2);
    wl2h[z] = (u16*)alloc((size_t)256 * 128 * 2);
    wl2l[z] = (u16*)alloc((size_t)256 * 128 * 2);
    wl3h[z] = (u16*)alloc((size_t)128 * 64 * 2);
    wl3l[z] = (u16*)alloc((size_t)128 * 64 * 2);
  }
  // deg/cnt contiguous for one memset: [deg0|cnt0|deg1|cnt1]
  float* degcnt = (float*)alloc((size_t)4 * NN * 4);
  PreArgs P;
  PreFused PF;
  PF.x[0] = x_m; PF.x[1] = x_d;
  PF.data[0] = data_m; PF.data[1] = data_d;
  for (int z = 0; z < 2; ++z) {
    PF.ph[z] = hh[z]; PF.pl[z] = hl[z];
    PF.ei[z] = z ? ei_d : ei_m;
    PF.wbuf[z] = (float*)alloc((size_t)NE * 4);
    PF.deg[z] = degcnt + (size_t)2 * NN * z;
    PF.cnt[z] = (int*)(degcnt + (size_t)2 * NN * z + NN);
    P.ei[z] = PF.ei[z];
    P.wbuf[z] = PF.wbuf[z];
    P.deg[z] = PF.deg[z];
    P.cnt[z] = PF.cnt[z];
    P.edata[z]  = (int2*)alloc((size_t)NE * 8);
    P.dinv[z]   = (float*)alloc((size_t)NN * 4);
    P.colptr[z] = (int*)alloc((size_t)(NN + 1) * 4);
  }

  // ---- weight split table ----
  const float* Wsrc[10] = {Wg1, Wg2, lx1_w, lx2_w, lx3_w, Wd1, Wd2, ly1_w, ly2_w, ly3_w};
  u16* Thd[10] = {wg1h[0], wg2h[0], wl1h[0], wl2h[0], wl3h[0],
                  wg1h[1], wg2h[1], wl1h[1], wl2h[1], wl3h[1]};
  u16* Tld[10] = {wg1l[0], wg2l[0], wl1l[0], wl2l[0], wl3l[0],
                  wg1l[1], wg2l[1], wl1l[1], wl2l[1], wl3l[1]};
  int Ks[10] = {512, 512, 512, 256, 128, 512, 512, 512, 256, 128};
  int Ns[10] = {512, 512, 256, 128, 64, 512, 512, 256, 128, 64};
  int acc_t = 0;
  for (int m = 0; m < 10; ++m) {
    PF.wt.W[m] = Wsrc[m]; PF.wt.Th[m] = Thd[m]; PF.wt.Tl[m] = Tld[m];
    PF.wt.K[m] = Ks[m]; PF.wt.N[m] = Ns[m];
    PF.wt.toff[m] = acc_t;
    acc_t += (Ns[m] / 32) * (Ks[m] / 32);
  }
  PF.wt.toff[10] = acc_t;       // 1360
  int wthalf = acc_t / 2;       // 680

  int sb = (MP * FF / 4 + 255) / 256;  // 4032
  int eb = (NE + 255) / 256;           // 1000

  // ---- preprocessing: memset -> fused pre -> scan -> scatter ----
  hipMemsetAsync(degcnt, 0, (size_t)4 * NN * 4, stream);
  k_pre<<<dim3(sb + eb + wthalf, 1, 2), 256, 0, stream>>>(
      PF, sb, eb, wthalf, NN * FF, MP * FF, NE, NN);
  k_scan_dinv<<<dim3(1, 1, 2), 256, 0, stream>>>(P, NN);
  k_scatter<<<dim3(eb, 1, 2), 256, 0, stream>>>(P, NE);

  MMArgs MA;
  AggArgs GA;
  for (int z = 0; z < 2; ++z) {
    MA.bias[z] = nullptr; MA.C[z] = nullptr; MA.Ch[z] = nullptr; MA.Cl[z] = nullptr;
    GA.XWh[z] = xwh[z];
    GA.colptr[z] = P.colptr[z];
    GA.edata[z] = P.edata[z];
    GA.dinv[z] = P.dinv[z];
    GA.Hh[z] = hh[z]; GA.Hl[z] = hl[z];
  }

  // ---- GCN layer 1: XW (bf16-hi out) -> aggregate ----
  for (int z = 0; z < 2; ++z) {
    MA.Ah[z] = hh[z]; MA.Al[z] = hl[z];
    MA.Bh[z] = wg1h[z]; MA.Bl[z] = wg1l[z];
    MA.Ch[z] = xwh[z];
  }
  k_mm<false, false, 2, false, false><<<dim3(63, FF / 128, 2), 256, 0, stream>>>(MA, NN, FF, FF);
  GA.bias[0] = bg1; GA.bias[1] = bd1;
  k_aggregate<<<dim3(8000, 1, 2), 256, 0, stream>>>(GA);

  // ---- GCN layer 2 ----
  for (int z = 0; z < 2; ++z) { MA.Bh[z] = wg2h[z]; MA.Bl[z] = wg2l[z]; }
  k_mm<false, false, 2, false, false><<<dim3(63, FF / 128, 2), 256, 0, stream>>>(MA, NN, FF, FF);
  GA.bias[0] = bg2; GA.bias[1] = bd2;
  k_aggregate<<<dim3(8000, 1, 2), 256, 0, stream>>>(GA);

  // ---- MLP1: 512 -> 256, hi+lo planes out ----
  MA.bias[0] = lx1_b; MA.bias[1] = ly1_b;
  for (int z = 0; z < 2; ++z) {
    MA.Bh[z] = wl1h[z]; MA.Bl[z] = wl1l[z];
    MA.Ch[z] = p1h[z]; MA.Cl[z] = p1l[z];
  }
  k_mm<true, true, 1, false, false><<<dim3(63, 2, 2), 256, 0, stream>>>(MA, NN, 256, FF);

  // ---- MLP2: 256 -> 128 ----
  MA.bias[0] = lx2_b; MA.bias[1] = ly2_b;
  for (int z = 0; z < 2; ++z) {
    MA.Ah[z] = p1h[z]; MA.Al[z] = p1l[z];
    MA.Bh[z] = wl2h[z]; MA.Bl[z] = wl2l[z];
    MA.Ch[z] = p2h[z]; MA.Cl[z] = p2l[z];
  }
  k_mm<true, true, 1, false, false><<<dim3(63, 1, 2), 256, 0, stream>>>(MA, NN, 128, 256);

  // ---- MLP3: 128 -> 64 (N-guard) ----
  MA.bias[0] = lx3_b; MA.bias[1] = ly3_b;
  for (int z = 0; z < 2; ++z) {
    MA.Ah[z] = p2h[z]; MA.Al[z] = p2l[z];
    MA.Bh[z] = wl3h[z]; MA.Bl[z] = wl3l[z];
    MA.Ch[z] = fh[z]; MA.Cl[z] = fl[z];
  }
  k_mm<true, true, 1, true, false><<<dim3(63, 1, 2), 256, 0, stream>>>(MA, NN, 64, 128);

  // ---- scores = x @ y^T (nontemporal 256 MB write) ----
  MMArgs SC;
  SC.Ah[0] = fh[0]; SC.Al[0] = fl[0];
  SC.Bh[0] = fh[1]; SC.Bl[0] = fl[1];
  SC.Ah[1] = SC.Ah[0]; SC.Al[1] = SC.Al[0]; SC.Bh[1] = SC.Bh[0]; SC.Bl[1] = SC.Bl[0];
  SC.bias[0] = nullptr; SC.bias[1] = nullptr;
  SC.C[0] = out; SC.C[1] = out;
  SC.Ch[0] = SC.Ch[1] = nullptr; SC.Cl[0] = SC.Cl[1] = nullptr;
  k_mm<false, false, 0, true, true><<<dim3(63, 63, 1), 256, 0, stream>>>(SC, NN, NN, 64);
}

// Round 15
// 347.532 us; speedup vs baseline: 1.3475x; 1.0539x over previous
//
#include <hip/hip_runtime.h>

typedef unsigned short u16;
typedef unsigned int u32;
typedef __attribute__((ext_vector_type(8))) short bf16x8;
typedef __attribute__((ext_vector_type(4))) float f32x4;
typedef __attribute__((ext_vector_type(4))) unsigned short u16x4;
typedef __attribute__((ext_vector_type(2))) unsigned short u16x2;

static const int NN = 8000;    // nodes per graph (M == D)
static const int NE = 256000;  // edges per graph
static const int FF = 512;     // feature dim
static const int MP = 8064;    // 63 * 128 padded rows
static const int CAP = 128;    // edge bucket capacity (deg: mean 32, sd 5.7)

__device__ __forceinline__ u16 f2bf(float x) {
  union { float f; u32 u; } a; a.f = x;
  u32 r = a.u + 0x7FFF + ((a.u >> 16) & 1);  // RNE
  return (u16)(r >> 16);
}
__device__ __forceinline__ float bf2f(u16 b) {
  union { float f; u32 u; } a; a.u = ((u32)b) << 16;
  return a.f;
}

__device__ __forceinline__ void gload_lds16(const void* g, void* l) {
  __builtin_amdgcn_global_load_lds(
      (const __attribute__((address_space(1))) unsigned int*)g,
      (__attribute__((address_space(3))) unsigned int*)l, 16, 0, 0);
}

// ---------------- arg structs (blockIdx.z = graph where applicable) --------

struct WTAll {
  const float* W[10];
  u16* Th[10];
  u16* Tl[10];
  int K[10], N[10];
  int toff[11];
};

// fused preprocessing: act-split | edge-weight gather | weight splits
struct PreFused {
  const float* x[2];
  u16* ph[2];
  u16* pl[2];
  const float* data[2];
  const int* ei[2];
  float* wbuf[2];
  float* deg[2];   // zeroed by memset; accumulates sum(w)
  WTAll wt;
};

struct ScatArgs {
  const int* ei[2];
  const float* wbuf[2];
  const float* deg[2];
  int* cnt[2];     // zeroed by memset; bucket fill counts
  int2* edata[2];  // bucketed [node][CAP]: (src byte-offset, norm-bits)
};

struct MMArgs {
  const u16* Ah[2]; const u16* Al[2];
  const u16* Bh[2]; const u16* Bl[2];
  const float* bias[2];
  float* C[2];             // fp32 output (OUTMODE 0)
  u16* Ch[2]; u16* Cl[2];  // plane outputs (OUTMODE 1 = hi+lo, 2 = hi only)
};

struct AggArgs {
  const u16* XWh[2];       // bf16-hi XW planes [MP][FF]
  const int* cnt[2];
  const float* deg[2];
  const int2* edata[2];
  const float* bias[2];
  u16* Hh[2];
  u16* Hl[2];
};

// ---------------- fused preprocessing ----------------
// block ranges: [0,sb) act-split | [sb,sb+eb) edge weights | rest: W splits.

__global__ __launch_bounds__(256) void k_pre(PreFused a, int sb, int eb, int wthalf,
                                             int tot_in, int tot_pad, int E, int n) {
  int z = blockIdx.z;
  int b = blockIdx.x;
  int tid = threadIdx.x;
  if (b < sb) {
    int i = (b * 256 + tid) * 4;
    if (i >= tot_pad) return;
    float4 v = (i < tot_in) ? *(const float4*)&a.x[z][i] : make_float4(0.f, 0.f, 0.f, 0.f);
    u16x4 h, l;
#pragma unroll
    for (int e = 0; e < 4; ++e) {
      float x = (&v.x)[e];
      u16 hh = f2bf(x);
      h[e] = hh;
      l[e] = f2bf(x - bf2f(hh));
    }
    *(u16x4*)&a.ph[z][i] = h;
    *(u16x4*)&a.pl[z][i] = l;
  } else if (b < sb + eb) {
    int e = (b - sb) * 256 + tid;
    if (e >= E) return;
    const int* ei = a.ei[z];
    int r = ei[e];
    int c = ei[E + e];
    float w = fmaxf(a.data[z][(size_t)r * n + c], 0.0f);
    a.wbuf[z][e] = w;
    atomicAdd(&a.deg[z][c], w);
  } else {
    int bid = (b - sb - eb) + z * wthalf;
    int m = 0;
    while (bid >= a.wt.toff[m + 1]) ++m;
    int local = bid - a.wt.toff[m];
    int K = a.wt.K[m], N = a.wt.N[m];
    int ntn = N >> 5;
    int n0 = (local % ntn) * 32, k0 = (local / ntn) * 32;
    const float* W = a.wt.W[m];
    u16* Th = a.wt.Th[m];
    u16* Tl = a.wt.Tl[m];
    __shared__ float tile[32][33];
    int tx = tid & 31, ty = tid >> 5;
#pragma unroll
    for (int r = 0; r < 32; r += 8)
      tile[r + ty][tx] = W[(size_t)(k0 + r + ty) * N + n0 + tx];
    __syncthreads();
#pragma unroll
    for (int r = 0; r < 32; r += 8) {
      float v = tile[tx][r + ty];
      int nn = n0 + r + ty, k = k0 + tx;
      u16 h = f2bf(v);
      Th[(size_t)nn * K + k] = h;
      Tl[(size_t)nn * K + k] = f2bf(v - bf2f(h));
    }
  }
}

// ---------------- bf16x3 MFMA GEMM body ----------------
// OUTMODE: 0 = fp32 C, 1 = bf16 hi+lo planes, 2 = bf16 hi-only plane.

template <bool BIAS, bool RELU, int OUTMODE, bool GUARD, bool NT>
__device__ __forceinline__ void mm_body(char* smem, const MMArgs& a,
                                        int M, int N, int K,
                                        int bx, int by, int z) {
  u16 (*lds)[4][4096] = (u16(*)[4][4096])smem;
  float* ct = (float*)smem;

  int tid = threadIdx.x;
  int wv = tid >> 6, ln = tid & 63;
  int l15 = ln & 15, l4 = ln >> 4;
  int m0 = bx * 128, n0 = by * 128;
  int wm = (wv & 1) * 64, wn = (wv >> 1) * 64;
  const u16* gb = (wv == 0) ? a.Ah[z] : (wv == 1) ? a.Al[z] : (wv == 2) ? a.Bh[z] : a.Bl[z];
  int row0 = (wv < 2) ? m0 : n0;

  f32x4 acc[4][4];
  f32x4 zz = {0.f, 0.f, 0.f, 0.f};
#pragma unroll
  for (int i = 0; i < 4; ++i)
#pragma unroll
    for (int j = 0; j < 4; ++j) acc[i][j] = zz;

  auto stage = [&](int d, int k0) {
#pragma unroll
    for (int it = 0; it < 8; ++it) {
      int slot = it * 64 + ln;
      int r = slot >> 2, c = slot & 3;
      int gc = c ^ ((r >> 2) & 3);
      gload_lds16(gb + ((size_t)(row0 + r) * K + k0 + gc * 8),
                  &lds[d][wv][it * 512]);
    }
  };

  auto compute = [&](int d) {
    bf16x8 ah[4], al[4], bh[4], bl[4];
#pragma unroll
    for (int i = 0; i < 4; ++i) {
      int r = wm + i * 16 + l15;
      int off = r * 32 + ((l4 ^ ((r >> 2) & 3)) << 3);
      ah[i] = *(const bf16x8*)&lds[d][0][off];
      al[i] = *(const bf16x8*)&lds[d][1][off];
    }
#pragma unroll
    for (int j = 0; j < 4; ++j) {
      int r = wn + j * 16 + l15;
      int off = r * 32 + ((l4 ^ ((r >> 2) & 3)) << 3);
      bh[j] = *(const bf16x8*)&lds[d][2][off];
      bl[j] = *(const bf16x8*)&lds[d][3][off];
    }
#pragma unroll
    for (int i = 0; i < 4; ++i)
#pragma unroll
      for (int j = 0; j < 4; ++j) {
        acc[i][j] = __builtin_amdgcn_mfma_f32_16x16x32_bf16(ah[i], bh[j], acc[i][j], 0, 0, 0);
        acc[i][j] = __builtin_amdgcn_mfma_f32_16x16x32_bf16(al[i], bh[j], acc[i][j], 0, 0, 0);
        acc[i][j] = __builtin_amdgcn_mfma_f32_16x16x32_bf16(ah[i], bl[j], acc[i][j], 0, 0, 0);
      }
  };

  stage(0, 0);
  __syncthreads();
  int nk = K >> 5;
  for (int t = 0; t < nk; ++t) {
    int cur = t & 1;
    if (t + 1 < nk) stage(cur ^ 1, (t + 1) << 5);
    compute(cur);
    __syncthreads();
  }

  // ---- epilogue: acc (D layout col=lane&15, row=4*(lane>>4)+reg) -> LDS ----
#pragma unroll
  for (int i = 0; i < 4; ++i)
#pragma unroll
    for (int rr = 0; rr < 4; ++rr) {
      int row = wm + i * 16 + l4 * 4 + rr;
#pragma unroll
      for (int j = 0; j < 4; ++j) {
        int col = wn + l15 + j * 16;
        ct[row * 132 + col] = acc[i][j][rr];
      }
    }
  __syncthreads();

  int tcol = (tid & 31) * 4;
  int trow = tid >> 5;
#pragma unroll
  for (int p = 0; p < 16; ++p) {
    int row = p * 8 + trow;
    int m = m0 + row;
    int n = n0 + tcol;
    if (GUARD && n >= N) continue;
    f32x4 v = *(f32x4*)&ct[row * 132 + tcol];
    float o[4];
#pragma unroll
    for (int e = 0; e < 4; ++e) {
      float x = v[e];
      if (BIAS) x += a.bias[z][n + e];
      if (RELU) x = fmaxf(x, 0.0f);
      o[e] = x;
    }
    if (OUTMODE >= 1) {
      u16x4 hh, ll;
      if (m < M) {
#pragma unroll
        for (int e = 0; e < 4; ++e) {
          u16 h = f2bf(o[e]);
          hh[e] = h;
          if (OUTMODE == 1) ll[e] = f2bf(o[e] - bf2f(h));
        }
      } else {
#pragma unroll
        for (int e = 0; e < 4; ++e) { hh[e] = 0; ll[e] = 0; }
      }
      *(u16x4*)&a.Ch[z][(size_t)m * N + n] = hh;
      if (OUTMODE == 1) *(u16x4*)&a.Cl[z][(size_t)m * N + n] = ll;
    } else {
      if (m < M) {
        f32x4 o4 = {o[0], o[1], o[2], o[3]};
        if (NT)
          __builtin_nontemporal_store(o4, (f32x4*)&a.C[z][(size_t)m * N + n]);
        else
          *(f32x4*)&a.C[z][(size_t)m * N + n] = o4;
      }
    }
  }
}

template <bool BIAS, bool RELU, int OUTMODE, bool GUARD, bool NT>
__global__ __launch_bounds__(256) void k_mm(MMArgs a, int M, int N, int K) {
  __shared__ __align__(16) char smem[67584];
  mm_body<BIAS, RELU, OUTMODE, GUARD, NT>(smem, a, M, N, K,
                                          blockIdx.x, blockIdx.y, blockIdx.z);
}

// ---------------- fused GCN1 GEMM + bucket scatter ----------------
// blocks [0,504): GEMM1 (63 x 4 x 2 flattened). blocks [504, 504+2000):
// scatter edges into fixed-CAP buckets (independent of the GEMM; both only
// depend on k_pre). dinv recomputed on the fly as 1/sqrt(1+deg).

__global__ __launch_bounds__(256) void k_g1s(MMArgs ma, ScatArgs sa, int E) {
  __shared__ __align__(16) char smem[67584];
  int f = blockIdx.x;
  if (f < 504) {
    int z = f / 252, rem = f % 252;
    mm_body<false, false, 2, false, false>(smem, ma, NN, FF, FF,
                                           rem % 63, rem / 63, z);
  } else {
    int s = f - 504;
    int z = s >= 1000 ? 1 : 0;
    int e = (s - z * 1000) * 256 + threadIdx.x;
    if (e >= E) return;
    const int* ei = sa.ei[z];
    int r = ei[e], c = ei[E + e];
    float w = sa.wbuf[z][e];
    float dr = 1.0f / sqrtf(1.0f + sa.deg[z][r]);
    float dc = 1.0f / sqrtf(1.0f + sa.deg[z][c]);
    int slot = atomicAdd(&sa.cnt[z][c], 1);
    int2 sn;
    sn.x = r << 10;  // pre-scaled byte offset: r * FF * 2
    sn.y = __float_as_int(dr * w * dc);
    sa.edata[z][(size_t)c * CAP + slot] = sn;
  }
}

// ---------------- sparse aggregation: static, bf16 gathers, L2 slabs -------
// Bucketed edata [node][CAP]; count from cnt. XW gathered as bf16-hi: chunk
// slab = 8000*128*2B = 2MB; both graphs fit one XCD L2 under chunk = bid&3.
// One wave = one (node, 128-elem chunk); u16x2/lane; edata.x is a pre-scaled
// row byte offset. LDS edge staging, 8-way unroll with 8 independent
// accumulator pairs; no atomics; static single-writer mapping (G16-safe).

__global__ __launch_bounds__(256) void k_aggregate(AggArgs a) {
  __shared__ int2 ebuf[4][64];
  int z = blockIdx.z;
  int bid = blockIdx.x;               // 0..7999
  int wv = threadIdx.x >> 6, ln = threadIdx.x & 63;
  int chunk = bid & 3;                // 4 chunks x 128 elems (2MB slab)
  int c = (bid >> 2) * 4 + wv;        // node 0..7999
  int fo = chunk * 128 + ln * 2;
  const char* XWb = (const char*)a.XWh[z];
  size_t fo2 = (size_t)fo * 2;        // byte offset within row
  const int2* ed = a.edata[z] + (size_t)c * CAP;
  int cn = a.cnt[z][c];
  float di = 1.0f / sqrtf(1.0f + a.deg[z][c]);
  float sl = di * di;

  u16x2 sh = *(const u16x2*)(XWb + (size_t)c * 1024 + fo2);
  float xa[8], ya[8];
  xa[0] = bf2f(sh[0]) * sl; ya[0] = bf2f(sh[1]) * sl;
#pragma unroll
  for (int q = 1; q < 8; ++q) { xa[q] = 0.f; ya[q] = 0.f; }

  for (int base = 0; base < cn; base += 64) {
    if (base + ln < cn) ebuf[wv][ln] = ed[base + ln];
    int rem = cn - base;
    int ne = rem < 64 ? rem : 64;
    int j = 0;
    for (; j + 8 <= ne; j += 8) {
      int2 d[8];
#pragma unroll
      for (int q = 0; q < 8; ++q) d[q] = ebuf[wv][j + q];
      u16x2 qv[8];
#pragma unroll
      for (int q = 0; q < 8; ++q)
        qv[q] = *(const u16x2*)(XWb + (size_t)(u32)d[q].x + fo2);
#pragma unroll
      for (int q = 0; q < 8; ++q) {
        float w = __int_as_float(d[q].y);
        xa[q] = fmaf(w, bf2f(qv[q][0]), xa[q]);
        ya[q] = fmaf(w, bf2f(qv[q][1]), ya[q]);
      }
    }
    for (; j < ne; ++j) {
      int2 d0 = ebuf[wv][j];
      u16x2 q0 = *(const u16x2*)(XWb + (size_t)(u32)d0.x + fo2);
      float w0 = __int_as_float(d0.y);
      xa[0] = fmaf(w0, bf2f(q0[0]), xa[0]); ya[0] = fmaf(w0, bf2f(q0[1]), ya[0]);
    }
  }

  float2 b2 = *(const float2*)&a.bias[z][fo];
  float ox = ((xa[0] + xa[1]) + (xa[2] + xa[3])) + ((xa[4] + xa[5]) + (xa[6] + xa[7]));
  float oy = ((ya[0] + ya[1]) + (ya[2] + ya[3])) + ((ya[4] + ya[5]) + (ya[6] + ya[7]));
  ox = fmaxf(ox + b2.x, 0.0f);
  oy = fmaxf(oy + b2.y, 0.0f);
  u16 hx = f2bf(ox), hy = f2bf(oy);
  u16x2 hh = {hx, hy};
  u16x2 ll = {f2bf(ox - bf2f(hx)), f2bf(oy - bf2f(hy))};
  *(u16x2*)&a.Hh[z][(size_t)c * FF + fo] = hh;
  *(u16x2*)&a.Hl[z][(size_t)c * FF + fo] = ll;
}

// ---------------- host orchestration ----------------

extern "C" void kernel_launch(void* const* d_in, const int* in_sizes, int n_in,
                              void* d_out, int out_size, void* d_ws, size_t ws_size,
                              hipStream_t stream) {
  const float* x_m    = (const float*)d_in[0];
  const float* x_d    = (const float*)d_in[1];
  const float* data_m = (const float*)d_in[2];
  const float* data_d = (const float*)d_in[3];
  const int*   ei_m   = (const int*)d_in[4];
  const int*   ei_d   = (const int*)d_in[5];
  const float* Wg1 = (const float*)d_in[6];
  const float* bg1 = (const float*)d_in[7];
  const float* Wg2 = (const float*)d_in[8];
  const float* bg2 = (const float*)d_in[9];
  const float* Wd1 = (const float*)d_in[10];
  const float* bd1 = (const float*)d_in[11];
  const float* Wd2 = (const float*)d_in[12];
  const float* bd2 = (const float*)d_in[13];
  const float* lx1_w = (const float*)d_in[14];
  const float* lx1_b = (const float*)d_in[15];
  const float* lx2_w = (const float*)d_in[16];
  const float* lx2_b = (const float*)d_in[17];
  const float* lx3_w = (const float*)d_in[18];
  const float* lx3_b = (const float*)d_in[19];
  const float* ly1_w = (const float*)d_in[20];
  const float* ly1_b = (const float*)d_in[21];
  const float* ly2_w = (const float*)d_in[22];
  const float* ly2_b = (const float*)d_in[23];
  const float* ly3_w = (const float*)d_in[24];
  const float* ly3_b = (const float*)d_in[25];
  float* out = (float*)d_out;

  char* base = (char*)d_ws;
  size_t off = 0;
  auto alloc = [&](size_t bytes) -> char* {
    char* p = base + off;
    off += (bytes + 255) & ~(size_t)255;
    return p;
  };
  u16* hh[2], *hl[2];
  for (int z = 0; z < 2; ++z) {
    hh[z] = (u16*)alloc((size_t)MP * FF * 2);
    hl[z] = (u16*)alloc((size_t)MP * FF * 2);
  }
  u16* xwh[2];  // bf16-hi XW (GCN GEMM output / aggregation input)
  for (int z = 0; z < 2; ++z) xwh[z] = (u16*)alloc((size_t)MP * FF * 2);
  u16* p1h[2], *p1l[2], *p2h[2], *p2l[2], *fh[2], *fl[2];
  for (int z = 0; z < 2; ++z) {
    p1h[z] = (u16*)alloc((size_t)MP * 256 * 2);
    p1l[z] = (u16*)alloc((size_t)MP * 256 * 2);
    p2h[z] = (u16*)alloc((size_t)MP * 128 * 2);
    p2l[z] = (u16*)alloc((size_t)MP * 128 * 2);
    fh[z]  = (u16*)alloc((size_t)MP * 64 * 2);
    fl[z]  = (u16*)alloc((size_t)MP * 64 * 2);
  }
  u16 *wg1h[2], *wg1l[2], *wg2h[2], *wg2l[2], *wl1h[2], *wl1l[2],
      *wl2h[2], *wl2l[2], *wl3h[2], *wl3l[2];
  for (int z = 0; z < 2; ++z) {
    wg1h[z] = (u16*)alloc((size_t)512 * 512 * 2);
    wg1l[z] = (u16*)alloc((size_t)512 * 512 * 2);
    wg2h[z] = (u16*)alloc((size_t)512 * 512 * 2);
    wg2l[z] = (u16*)alloc((size_t)512 * 512 * 2);
    wl1h[z] = (u16*)alloc((size_t)512 * 256 * 2);
    wl1l[z] = (u16*)alloc((size_t)512 * 256 * 2);
    wl2h[z] = (u16*)alloc((size_t)256 * 128 * 2);
    wl2l[z] = (u16*)alloc((size_t)256 * 128 * 2);
    wl3h[z] = (u16*)alloc((size_t)128 * 64 * 2);
    wl3l[z] = (u16*)alloc((size_t)128 * 64 * 2);
  }
  // deg/cnt contiguous for one memset: [deg0|cnt0|deg1|cnt1]
  float* degcnt = (float*)alloc((size_t)4 * NN * 4);
  PreFused PF;
  ScatArgs SA;
  PF.x[0] = x_m; PF.x[1] = x_d;
  PF.data[0] = data_m; PF.data[1] = data_d;
  for (int z = 0; z < 2; ++z) {
    PF.ph[z] = hh[z]; PF.pl[z] = hl[z];
    PF.ei[z] = z ? ei_d : ei_m;
    PF.wbuf[z] = (float*)alloc((size_t)NE * 4);
    PF.deg[z] = degcnt + (size_t)2 * NN * z;
    SA.ei[z] = PF.ei[z];
    SA.wbuf[z] = PF.wbuf[z];
    SA.deg[z] = PF.deg[z];
    SA.cnt[z] = (int*)(degcnt + (size_t)2 * NN * z + NN);
    SA.edata[z] = (int2*)alloc((size_t)NN * CAP * 8);
  }

  // ---- weight split table ----
  const float* Wsrc[10] = {Wg1, Wg2, lx1_w, lx2_w, lx3_w, Wd1, Wd2, ly1_w, ly2_w, ly3_w};
  u16* Thd[10] = {wg1h[0], wg2h[0], wl1h[0], wl2h[0], wl3h[0],
                  wg1h[1], wg2h[1], wl1h[1], wl2h[1], wl3h[1]};
  u16* Tld[10] = {wg1l[0], wg2l[0], wl1l[0], wl2l[0], wl3l[0],
                  wg1l[1], wg2l[1], wl1l[1], wl2l[1], wl3l[1]};
  int Ks[10] = {512, 512, 512, 256, 128, 512, 512, 512, 256, 128};
  int Ns[10] = {512, 512, 256, 128, 64, 512, 512, 256, 128, 64};
  int acc_t = 0;
  for (int m = 0; m < 10; ++m) {
    PF.wt.W[m] = Wsrc[m]; PF.wt.Th[m] = Thd[m]; PF.wt.Tl[m] = Tld[m];
    PF.wt.K[m] = Ks[m]; PF.wt.N[m] = Ns[m];
    PF.wt.toff[m] = acc_t;
    acc_t += (Ns[m] / 32) * (Ks[m] / 32);
  }
  PF.wt.toff[10] = acc_t;       // 1360
  int wthalf = acc_t / 2;       // 680

  int sb = (MP * FF / 4 + 255) / 256;  // 4032
  int eb = (NE + 255) / 256;           // 1000

  MMArgs MA;
  AggArgs GA;
  for (int z = 0; z < 2; ++z) {
    MA.bias[z] = nullptr; MA.C[z] = nullptr; MA.Ch[z] = nullptr; MA.Cl[z] = nullptr;
    GA.XWh[z] = xwh[z];
    GA.cnt[z] = SA.cnt[z];
    GA.deg[z] = SA.deg[z];
    GA.edata[z] = SA.edata[z];
    GA.Hh[z] = hh[z]; GA.Hl[z] = hl[z];
  }

  // ---- preprocessing: memset -> fused pre ----
  hipMemsetAsync(degcnt, 0, (size_t)4 * NN * 4, stream);
  k_pre<<<dim3(sb + eb + wthalf, 1, 2), 256, 0, stream>>>(
      PF, sb, eb, wthalf, NN * FF, MP * FF, NE, NN);

  // ---- GCN1 GEMM fused with bucket scatter ----
  for (int z = 0; z < 2; ++z) {
    MA.Ah[z] = hh[z]; MA.Al[z] = hl[z];
    MA.Bh[z] = wg1h[z]; MA.Bl[z] = wg1l[z];
    MA.Ch[z] = xwh[z];
  }
  k_g1s<<<dim3(504 + 2 * eb, 1, 1), 256, 0, stream>>>(MA, SA, NE);
  GA.bias[0] = bg1; GA.bias[1] = bd1;
  k_aggregate<<<dim3(8000, 1, 2), 256, 0, stream>>>(GA);

  // ---- GCN layer 2 ----
  for (int z = 0; z < 2; ++z) { MA.Bh[z] = wg2h[z]; MA.Bl[z] = wg2l[z]; }
  k_mm<false, false, 2, false, false><<<dim3(63, FF / 128, 2), 256, 0, stream>>>(MA, NN, FF, FF);
  GA.bias[0] = bg2; GA.bias[1] = bd2;
  k_aggregate<<<dim3(8000, 1, 2), 256, 0, stream>>>(GA);

  // ---- MLP1: 512 -> 256, hi+lo planes out ----
  MA.bias[0] = lx1_b; MA.bias[1] = ly1_b;
  for (int z = 0; z < 2; ++z) {
    MA.Bh[z] = wl1h[z]; MA.Bl[z] = wl1l[z];
    MA.Ch[z] = p1h[z]; MA.Cl[z] = p1l[z];
  }
  k_mm<true, true, 1, false, false><<<dim3(63, 2, 2), 256, 0, stream>>>(MA, NN, 256, FF);

  // ---- MLP2: 256 -> 128 ----
  MA.bias[0] = lx2_b; MA.bias[1] = ly2_b;
  for (int z = 0; z < 2; ++z) {
    MA.Ah[z] = p1h[z]; MA.Al[z] = p1l[z];
    MA.Bh[z] = wl2h[z]; MA.Bl[z] = wl2l[z];
    MA.Ch[z] = p2h[z]; MA.Cl[z] = p2l[z];
  }
  k_mm<true, true, 1, false, false><<<dim3(63, 1, 2), 256, 0, stream>>>(MA, NN, 128, 256);

  // ---- MLP3: 128 -> 64 (N-guard) ----
  MA.bias[0] = lx3_b; MA.bias[1] = ly3_b;
  for (int z = 0; z < 2; ++z) {
    MA.Ah[z] = p2h[z]; MA.Al[z] = p2l[z];
    MA.Bh[z] = wl3h[z]; MA.Bl[z] = wl3l[z];
    MA.Ch[z] = fh[z]; MA.Cl[z] = fl[z];
  }
  k_mm<true, true, 1, true, false><<<dim3(63, 1, 2), 256, 0, stream>>>(MA, NN, 64, 128);

  // ---- scores = x @ y^T (nontemporal 256 MB write) ----
  MMArgs SC;
  SC.Ah[0] = fh[0]; SC.Al[0] = fl[0];
  SC.Bh[0] = fh[1]; SC.Bl[0] = fl[1];
  SC.Ah[1] = SC.Ah[0]; SC.Al[1] = SC.Al[0]; SC.Bh[1] = SC.Bh[0]; SC.Bl[1] = SC.Bl[0];
  SC.bias[0] = nullptr; SC.bias[1] = nullptr;
  SC.C[0] = out; SC.C[1] = out;
  SC.Ch[0] = SC.Ch[1] = nullptr; SC.Cl[0] = SC.Cl[1] = nullptr;
  k_mm<false, false, 0, true, true><<<dim3(63, 63, 1), 256, 0, stream>>>(SC, NN, NN, 64);
}

// Round 16
// 338.079 us; speedup vs baseline: 1.3852x; 1.0280x over previous
//
#include <hip/hip_runtime.h>

typedef unsigned short u16;
typedef unsigned int u32;
typedef __attribute__((ext_vector_type(8))) short bf16x8;
typedef __attribute__((ext_vector_type(4))) float f32x4;
typedef __attribute__((ext_vector_type(4))) unsigned short u16x4;
typedef __attribute__((ext_vector_type(2))) unsigned short u16x2;

static const int NN = 8000;    // nodes per graph (M == D)
static const int NE = 256000;  // edges per graph
static const int FF = 512;     // feature dim
static const int MP = 8064;    // 63 * 128 padded rows
static const int CAP = 128;    // edge bucket capacity (deg: mean 32, sd 5.7)

__device__ __forceinline__ u16 f2bf(float x) {
  union { float f; u32 u; } a; a.f = x;
  u32 r = a.u + 0x7FFF + ((a.u >> 16) & 1);  // RNE
  return (u16)(r >> 16);
}
__device__ __forceinline__ float bf2f(u16 b) {
  union { float f; u32 u; } a; a.u = ((u32)b) << 16;
  return a.f;
}

__device__ __forceinline__ void gload_lds16(const void* g, void* l) {
  __builtin_amdgcn_global_load_lds(
      (const __attribute__((address_space(1))) unsigned int*)g,
      (__attribute__((address_space(3))) unsigned int*)l, 16, 0, 0);
}

// ---------------- arg structs (blockIdx.z = graph where applicable) --------

struct WTAll {
  const float* W[10];
  u16* Th[10];
  u16* Tl[10];
  int K[10], N[10];
  int toff[11];
};

// fused preprocessing: act-split | edge-weight gather | weight splits
struct PreFused {
  const float* x[2];
  u16* ph[2];
  u16* pl[2];
  const float* data[2];
  const int* ei[2];
  float* wbuf[2];
  float* deg[2];   // zeroed by memset; accumulates sum(w)
  WTAll wt;
};

struct ScatArgs {
  const int* ei[2];
  const float* wbuf[2];
  const float* deg[2];
  int* cnt[2];     // zeroed by memset; bucket fill counts
  int2* edata[2];  // bucketed [node][CAP]: (src byte-offset, norm-bits)
};

struct MMArgs {
  const u16* Ah[2]; const u16* Al[2];
  const u16* Bh[2]; const u16* Bl[2];
  const float* bias[2];
  float* C[2];             // fp32 output (OUTMODE 0)
  u16* Ch[2]; u16* Cl[2];  // plane outputs (OUTMODE 1 = hi+lo, 2 = hi only)
};

struct AggArgs {
  const u16* XWh[2];       // bf16-hi XW planes [MP][FF]
  const int* cnt[2];
  const float* deg[2];
  const int2* edata[2];
  const float* bias[2];
  u16* Hh[2];
  u16* Hl[2];
};

// ---------------- fused preprocessing ----------------
// block ranges: [0,sb) act-split | [sb,sb+eb) edge weights | rest: W splits.

__global__ __launch_bounds__(256) void k_pre(PreFused a, int sb, int eb, int wthalf,
                                             int tot_in, int tot_pad, int E, int n) {
  int z = blockIdx.z;
  int b = blockIdx.x;
  int tid = threadIdx.x;
  if (b < sb) {
    int i = (b * 256 + tid) * 4;
    if (i >= tot_pad) return;
    float4 v = (i < tot_in) ? *(const float4*)&a.x[z][i] : make_float4(0.f, 0.f, 0.f, 0.f);
    u16x4 h, l;
#pragma unroll
    for (int e = 0; e < 4; ++e) {
      float x = (&v.x)[e];
      u16 hh = f2bf(x);
      h[e] = hh;
      l[e] = f2bf(x - bf2f(hh));
    }
    *(u16x4*)&a.ph[z][i] = h;
    *(u16x4*)&a.pl[z][i] = l;
  } else if (b < sb + eb) {
    int e = (b - sb) * 256 + tid;
    if (e >= E) return;
    const int* ei = a.ei[z];
    int r = ei[e];
    int c = ei[E + e];
    float w = fmaxf(a.data[z][(size_t)r * n + c], 0.0f);
    a.wbuf[z][e] = w;
    atomicAdd(&a.deg[z][c], w);
  } else {
    int bid = (b - sb - eb) + z * wthalf;
    int m = 0;
    while (bid >= a.wt.toff[m + 1]) ++m;
    int local = bid - a.wt.toff[m];
    int K = a.wt.K[m], N = a.wt.N[m];
    int ntn = N >> 5;
    int n0 = (local % ntn) * 32, k0 = (local / ntn) * 32;
    const float* W = a.wt.W[m];
    u16* Th = a.wt.Th[m];
    u16* Tl = a.wt.Tl[m];
    __shared__ float tile[32][33];
    int tx = tid & 31, ty = tid >> 5;
#pragma unroll
    for (int r = 0; r < 32; r += 8)
      tile[r + ty][tx] = W[(size_t)(k0 + r + ty) * N + n0 + tx];
    __syncthreads();
#pragma unroll
    for (int r = 0; r < 32; r += 8) {
      float v = tile[tx][r + ty];
      int nn = n0 + r + ty, k = k0 + tx;
      u16 h = f2bf(v);
      Th[(size_t)nn * K + k] = h;
      Tl[(size_t)nn * K + k] = f2bf(v - bf2f(h));
    }
  }
}

// ---------------- bf16x3 MFMA GEMM body ----------------
// OUTMODE: 0 = fp32 C, 1 = bf16 hi+lo planes, 2 = bf16 hi-only plane.

template <bool BIAS, bool RELU, int OUTMODE, bool GUARD, bool NT>
__device__ __forceinline__ void mm_body(char* smem, const MMArgs& a,
                                        int M, int N, int K,
                                        int bx, int by, int z) {
  u16 (*lds)[4][4096] = (u16(*)[4][4096])smem;
  float* ct = (float*)smem;

  int tid = threadIdx.x;
  int wv = tid >> 6, ln = tid & 63;
  int l15 = ln & 15, l4 = ln >> 4;
  int m0 = bx * 128, n0 = by * 128;
  int wm = (wv & 1) * 64, wn = (wv >> 1) * 64;
  const u16* gb = (wv == 0) ? a.Ah[z] : (wv == 1) ? a.Al[z] : (wv == 2) ? a.Bh[z] : a.Bl[z];
  int row0 = (wv < 2) ? m0 : n0;

  f32x4 acc[4][4];
  f32x4 zz = {0.f, 0.f, 0.f, 0.f};
#pragma unroll
  for (int i = 0; i < 4; ++i)
#pragma unroll
    for (int j = 0; j < 4; ++j) acc[i][j] = zz;

  auto stage = [&](int d, int k0) {
#pragma unroll
    for (int it = 0; it < 8; ++it) {
      int slot = it * 64 + ln;
      int r = slot >> 2, c = slot & 3;
      int gc = c ^ ((r >> 2) & 3);
      gload_lds16(gb + ((size_t)(row0 + r) * K + k0 + gc * 8),
                  &lds[d][wv][it * 512]);
    }
  };

  auto compute = [&](int d) {
    bf16x8 ah[4], al[4], bh[4], bl[4];
#pragma unroll
    for (int i = 0; i < 4; ++i) {
      int r = wm + i * 16 + l15;
      int off = r * 32 + ((l4 ^ ((r >> 2) & 3)) << 3);
      ah[i] = *(const bf16x8*)&lds[d][0][off];
      al[i] = *(const bf16x8*)&lds[d][1][off];
    }
#pragma unroll
    for (int j = 0; j < 4; ++j) {
      int r = wn + j * 16 + l15;
      int off = r * 32 + ((l4 ^ ((r >> 2) & 3)) << 3);
      bh[j] = *(const bf16x8*)&lds[d][2][off];
      bl[j] = *(const bf16x8*)&lds[d][3][off];
    }
#pragma unroll
    for (int i = 0; i < 4; ++i)
#pragma unroll
      for (int j = 0; j < 4; ++j) {
        acc[i][j] = __builtin_amdgcn_mfma_f32_16x16x32_bf16(ah[i], bh[j], acc[i][j], 0, 0, 0);
        acc[i][j] = __builtin_amdgcn_mfma_f32_16x16x32_bf16(al[i], bh[j], acc[i][j], 0, 0, 0);
        acc[i][j] = __builtin_amdgcn_mfma_f32_16x16x32_bf16(ah[i], bl[j], acc[i][j], 0, 0, 0);
      }
  };

  stage(0, 0);
  __syncthreads();
  int nk = K >> 5;
  for (int t = 0; t < nk; ++t) {
    int cur = t & 1;
    if (t + 1 < nk) stage(cur ^ 1, (t + 1) << 5);
    compute(cur);
    __syncthreads();
  }

  // ---- epilogue: acc (D layout col=lane&15, row=4*(lane>>4)+reg) -> LDS ----
#pragma unroll
  for (int i = 0; i < 4; ++i)
#pragma unroll
    for (int rr = 0; rr < 4; ++rr) {
      int row = wm + i * 16 + l4 * 4 + rr;
#pragma unroll
      for (int j = 0; j < 4; ++j) {
        int col = wn + l15 + j * 16;
        ct[row * 132 + col] = acc[i][j][rr];
      }
    }
  __syncthreads();

  int tcol = (tid & 31) * 4;
  int trow = tid >> 5;
#pragma unroll
  for (int p = 0; p < 16; ++p) {
    int row = p * 8 + trow;
    int m = m0 + row;
    int n = n0 + tcol;
    if (GUARD && n >= N) continue;
    f32x4 v = *(f32x4*)&ct[row * 132 + tcol];
    float o[4];
#pragma unroll
    for (int e = 0; e < 4; ++e) {
      float x = v[e];
      if (BIAS) x += a.bias[z][n + e];
      if (RELU) x = fmaxf(x, 0.0f);
      o[e] = x;
    }
    if (OUTMODE >= 1) {
      u16x4 hh, ll;
      if (m < M) {
#pragma unroll
        for (int e = 0; e < 4; ++e) {
          u16 h = f2bf(o[e]);
          hh[e] = h;
          if (OUTMODE == 1) ll[e] = f2bf(o[e] - bf2f(h));
        }
      } else {
#pragma unroll
        for (int e = 0; e < 4; ++e) { hh[e] = 0; ll[e] = 0; }
      }
      *(u16x4*)&a.Ch[z][(size_t)m * N + n] = hh;
      if (OUTMODE == 1) *(u16x4*)&a.Cl[z][(size_t)m * N + n] = ll;
    } else {
      if (m < M) {
        f32x4 o4 = {o[0], o[1], o[2], o[3]};
        if (NT)
          __builtin_nontemporal_store(o4, (f32x4*)&a.C[z][(size_t)m * N + n]);
        else
          *(f32x4*)&a.C[z][(size_t)m * N + n] = o4;
      }
    }
  }
}

template <bool BIAS, bool RELU, int OUTMODE, bool GUARD, bool NT>
__global__ __launch_bounds__(256) void k_mm(MMArgs a, int M, int N, int K) {
  __shared__ __align__(16) char smem[67584];
  mm_body<BIAS, RELU, OUTMODE, GUARD, NT>(smem, a, M, N, K,
                                          blockIdx.x, blockIdx.y, blockIdx.z);
}

// ---------------- fused GCN1 GEMM + bucket scatter ----------------

__global__ __launch_bounds__(256) void k_g1s(MMArgs ma, ScatArgs sa, int E) {
  __shared__ __align__(16) char smem[67584];
  int f = blockIdx.x;
  if (f < 504) {
    int z = f / 252, rem = f % 252;
    mm_body<false, false, 2, false, false>(smem, ma, NN, FF, FF,
                                           rem % 63, rem / 63, z);
  } else {
    int s = f - 504;
    int z = s >= 1000 ? 1 : 0;
    int e = (s - z * 1000) * 256 + threadIdx.x;
    if (e >= E) return;
    const int* ei = sa.ei[z];
    int r = ei[e], c = ei[E + e];
    float w = sa.wbuf[z][e];
    float dr = 1.0f / sqrtf(1.0f + sa.deg[z][r]);
    float dc = 1.0f / sqrtf(1.0f + sa.deg[z][c]);
    int slot = atomicAdd(&sa.cnt[z][c], 1);
    int2 sn;
    sn.x = r << 10;  // pre-scaled byte offset: r * FF * 2
    sn.y = __float_as_int(dr * w * dc);
    sa.edata[z][(size_t)c * CAP + slot] = sn;
  }
}

// ---------------- score GEMM: 128x128 tile, K=64, 4 blocks/CU -------------
// Single-buffered staging (32KB) + half-tile epilogue (64x132 f32 = 33KB,
// overlays staging) -> 33.8KB LDS; launch_bounds(256,4) caps VGPR at 128
// (b-fragments loaded per-j). Write-bound: 2x blocks in flight vs k_mm.

__global__ __launch_bounds__(256, 4) void k_score(MMArgs a, int M, int N, int K) {
  __shared__ __align__(16) char smem[33792];
  u16 (*lds)[4096] = (u16(*)[4096])smem;  // [plane][128*32]
  float* ct = (float*)smem;               // 64 x 132 half tile

  int tid = threadIdx.x;
  int wv = tid >> 6, ln = tid & 63;
  int l15 = ln & 15, l4 = ln >> 4;
  int m0 = blockIdx.x * 128, n0 = blockIdx.y * 128;
  int wm = (wv & 1) * 64, wn = (wv >> 1) * 64;
  const u16* gb = (wv == 0) ? a.Ah[0] : (wv == 1) ? a.Al[0] : (wv == 2) ? a.Bh[0] : a.Bl[0];
  int row0 = (wv < 2) ? m0 : n0;

  f32x4 acc[4][4];
  f32x4 zz = {0.f, 0.f, 0.f, 0.f};
#pragma unroll
  for (int i = 0; i < 4; ++i)
#pragma unroll
    for (int j = 0; j < 4; ++j) acc[i][j] = zz;

  int nk = K >> 5;
  for (int t = 0; t < nk; ++t) {
    int k0 = t << 5;
#pragma unroll
    for (int it = 0; it < 8; ++it) {
      int slot = it * 64 + ln;
      int r = slot >> 2, c = slot & 3;
      int gc = c ^ ((r >> 2) & 3);
      gload_lds16(gb + ((size_t)(row0 + r) * K + k0 + gc * 8),
                  &lds[wv][it * 512]);
    }
    __syncthreads();
    bf16x8 ah[4], al[4];
#pragma unroll
    for (int i = 0; i < 4; ++i) {
      int r = wm + i * 16 + l15;
      int off = r * 32 + ((l4 ^ ((r >> 2) & 3)) << 3);
      ah[i] = *(const bf16x8*)&lds[0][off];
      al[i] = *(const bf16x8*)&lds[1][off];
    }
#pragma unroll
    for (int j = 0; j < 4; ++j) {
      int r = wn + j * 16 + l15;
      int off = r * 32 + ((l4 ^ ((r >> 2) & 3)) << 3);
      bf16x8 bh = *(const bf16x8*)&lds[2][off];
      bf16x8 bl = *(const bf16x8*)&lds[3][off];
#pragma unroll
      for (int i = 0; i < 4; ++i) {
        acc[i][j] = __builtin_amdgcn_mfma_f32_16x16x32_bf16(ah[i], bh, acc[i][j], 0, 0, 0);
        acc[i][j] = __builtin_amdgcn_mfma_f32_16x16x32_bf16(al[i], bh, acc[i][j], 0, 0, 0);
        acc[i][j] = __builtin_amdgcn_mfma_f32_16x16x32_bf16(ah[i], bl, acc[i][j], 0, 0, 0);
      }
    }
    __syncthreads();
  }

  int tcol = (tid & 31) * 4;
  int trow = tid >> 5;
#pragma unroll
  for (int h = 0; h < 2; ++h) {
    if ((wv & 1) == h) {
#pragma unroll
      for (int i = 0; i < 4; ++i)
#pragma unroll
        for (int rr = 0; rr < 4; ++rr) {
          int row = i * 16 + l4 * 4 + rr;
#pragma unroll
          for (int j = 0; j < 4; ++j)
            ct[row * 132 + wn + l15 + j * 16] = acc[i][j][rr];
        }
    }
    __syncthreads();
#pragma unroll
    for (int p = 0; p < 8; ++p) {
      int row = p * 8 + trow;
      int m = m0 + h * 64 + row;
      int n = n0 + tcol;
      if (n < N && m < M) {
        f32x4 v = *(f32x4*)&ct[row * 132 + tcol];
        __builtin_nontemporal_store(v, (f32x4*)&a.C[0][(size_t)m * N + n]);
      }
    }
    __syncthreads();
  }
}

// ---------------- sparse aggregation: half-wave u16x4 gathers --------------
// Lanes 0-31 process even edges, 32-63 odd edges; each lane gathers u16x4
// (4 elems, 8B) so one instruction covers an edge's 128-elem chunk per half.
// Halves merged at the end via one shfl_xor(32) per elem. Chunk slab = 2MB
// (chunk = bid&3, L2-resident both graphs). LDS edge staging; 4 independent
// accumulator banks; no atomics; static single-writer (G16-safe).

__global__ __launch_bounds__(256) void k_aggregate(AggArgs a) {
  __shared__ int2 ebuf[4][64];
  int z = blockIdx.z;
  int bid = blockIdx.x;               // 0..7999
  int wv = threadIdx.x >> 6, ln = threadIdx.x & 63;
  int half = ln >> 5, li = ln & 31;
  int chunk = bid & 3;                // 4 chunks x 128 elems (2MB slab)
  int c = (bid >> 2) * 4 + wv;        // node 0..7999
  int fo = chunk * 128 + li * 4;      // 4 elems/lane over 32 lanes
  const char* XWb = (const char*)a.XWh[z];
  size_t fo2 = (size_t)fo * 2;        // byte offset within row
  const int2* ed = a.edata[z] + (size_t)c * CAP;
  int cn = a.cnt[z][c];
  float di = 1.0f / sqrtf(1.0f + a.deg[z][c]);
  float sl = di * di;

  float acc4[4][4];                   // [bank][elem]
#pragma unroll
  for (int q = 0; q < 4; ++q)
#pragma unroll
    for (int e = 0; e < 4; ++e) acc4[q][e] = 0.f;

  for (int base = 0; base < cn; base += 64) {
    if (base + ln < cn) ebuf[wv][ln] = ed[base + ln];
    int rem = cn - base;
    int ne = rem < 64 ? rem : 64;
    int jj = 0;
    for (; jj + 8 <= ne; jj += 8) {   // 8 edges: 4 per half
      int2 d[4];
#pragma unroll
      for (int q = 0; q < 4; ++q) d[q] = ebuf[wv][jj + 2 * q + half];
      u16x4 qv[4];
#pragma unroll
      for (int q = 0; q < 4; ++q)
        qv[q] = *(const u16x4*)(XWb + (size_t)(u32)d[q].x + fo2);
#pragma unroll
      for (int q = 0; q < 4; ++q) {
        float w = __int_as_float(d[q].y);
#pragma unroll
        for (int e = 0; e < 4; ++e)
          acc4[q][e] = fmaf(w, bf2f(qv[q][e]), acc4[q][e]);
      }
    }
    for (int j = jj + half; j < ne; j += 2) {
      int2 d0 = ebuf[wv][j];
      u16x4 q0 = *(const u16x4*)(XWb + (size_t)(u32)d0.x + fo2);
      float w0 = __int_as_float(d0.y);
#pragma unroll
      for (int e = 0; e < 4; ++e)
        acc4[0][e] = fmaf(w0, bf2f(q0[e]), acc4[0][e]);
    }
  }

  float s[4];
#pragma unroll
  for (int e = 0; e < 4; ++e) {
    float v = (acc4[0][e] + acc4[1][e]) + (acc4[2][e] + acc4[3][e]);
    s[e] = v + __shfl_xor(v, 32);
  }

  if (half == 0) {
    u16x4 sh = *(const u16x4*)(XWb + (size_t)c * 1024 + fo2);
    f32x4 b4 = *(const f32x4*)&a.bias[z][fo];
    u16x4 hh, ll;
#pragma unroll
    for (int e = 0; e < 4; ++e) {
      float o = fmaxf(s[e] + sl * bf2f(sh[e]) + b4[e], 0.0f);
      u16 h = f2bf(o);
      hh[e] = h;
      ll[e] = f2bf(o - bf2f(h));
    }
    *(u16x4*)&a.Hh[z][(size_t)c * FF + fo] = hh;
    *(u16x4*)&a.Hl[z][(size_t)c * FF + fo] = ll;
  }
}

// ---------------- host orchestration ----------------

extern "C" void kernel_launch(void* const* d_in, const int* in_sizes, int n_in,
                              void* d_out, int out_size, void* d_ws, size_t ws_size,
                              hipStream_t stream) {
  const float* x_m    = (const float*)d_in[0];
  const float* x_d    = (const float*)d_in[1];
  const float* data_m = (const float*)d_in[2];
  const float* data_d = (const float*)d_in[3];
  const int*   ei_m   = (const int*)d_in[4];
  const int*   ei_d   = (const int*)d_in[5];
  const float* Wg1 = (const float*)d_in[6];
  const float* bg1 = (const float*)d_in[7];
  const float* Wg2 = (const float*)d_in[8];
  const float* bg2 = (const float*)d_in[9];
  const float* Wd1 = (const float*)d_in[10];
  const float* bd1 = (const float*)d_in[11];
  const float* Wd2 = (const float*)d_in[12];
  const float* bd2 = (const float*)d_in[13];
  const float* lx1_w = (const float*)d_in[14];
  const float* lx1_b = (const float*)d_in[15];
  const float* lx2_w = (const float*)d_in[16];
  const float* lx2_b = (const float*)d_in[17];
  const float* lx3_w = (const float*)d_in[18];
  const float* lx3_b = (const float*)d_in[19];
  const float* ly1_w = (const float*)d_in[20];
  const float* ly1_b = (const float*)d_in[21];
  const float* ly2_w = (const float*)d_in[22];
  const float* ly2_b = (const float*)d_in[23];
  const float* ly3_w = (const float*)d_in[24];
  const float* ly3_b = (const float*)d_in[25];
  float* out = (float*)d_out;

  char* base = (char*)d_ws;
  size_t off = 0;
  auto alloc = [&](size_t bytes) -> char* {
    char* p = base + off;
    off += (bytes + 255) & ~(size_t)255;
    return p;
  };
  u16* hh[2], *hl[2];
  for (int z = 0; z < 2; ++z) {
    hh[z] = (u16*)alloc((size_t)MP * FF * 2);
    hl[z] = (u16*)alloc((size_t)MP * FF * 2);
  }
  u16* xwh[2];  // bf16-hi XW (GCN GEMM output / aggregation input)
  for (int z = 0; z < 2; ++z) xwh[z] = (u16*)alloc((size_t)MP * FF * 2);
  u16* p1h[2], *p1l[2], *p2h[2], *p2l[2], *fh[2], *fl[2];
  for (int z = 0; z < 2; ++z) {
    p1h[z] = (u16*)alloc((size_t)MP * 256 * 2);
    p1l[z] = (u16*)alloc((size_t)MP * 256 * 2);
    p2h[z] = (u16*)alloc((size_t)MP * 128 * 2);
    p2l[z] = (u16*)alloc((size_t)MP * 128 * 2);
    fh[z]  = (u16*)alloc((size_t)MP * 64 * 2);
    fl[z]  = (u16*)alloc((size_t)MP * 64 * 2);
  }
  u16 *wg1h[2], *wg1l[2], *wg2h[2], *wg2l[2], *wl1h[2], *wl1l[2],
      *wl2h[2], *wl2l[2], *wl3h[2], *wl3l[2];
  for (int z = 0; z < 2; ++z) {
    wg1h[z] = (u16*)alloc((size_t)512 * 512 * 2);
    wg1l[z] = (u16*)alloc((size_t)512 * 512 * 2);
    wg2h[z] = (u16*)alloc((size_t)512 * 512 * 2);
    wg2l[z] = (u16*)alloc((size_t)512 * 512 * 2);
    wl1h[z] = (u16*)alloc((size_t)512 * 256 * 2);
    wl1l[z] = (u16*)alloc((size_t)512 * 256 * 2);
    wl2h[z] = (u16*)alloc((size_t)256 * 128 * 2);
    wl2l[z] = (u16*)alloc((size_t)256 * 128 * 2);
    wl3h[z] = (u16*)alloc((size_t)128 * 64 * 2);
    wl3l[z] = (u16*)alloc((size_t)128 * 64 * 2);
  }
  // deg/cnt contiguous for one memset: [deg0|cnt0|deg1|cnt1]
  float* degcnt = (float*)alloc((size_t)4 * NN * 4);
  PreFused PF;
  ScatArgs SA;
  PF.x[0] = x_m; PF.x[1] = x_d;
  PF.data[0] = data_m; PF.data[1] = data_d;
  for (int z = 0; z < 2; ++z) {
    PF.ph[z] = hh[z]; PF.pl[z] = hl[z];
    PF.ei[z] = z ? ei_d : ei_m;
    PF.wbuf[z] = (float*)alloc((size_t)NE * 4);
    PF.deg[z] = degcnt + (size_t)2 * NN * z;
    SA.ei[z] = PF.ei[z];
    SA.wbuf[z] = PF.wbuf[z];
    SA.deg[z] = PF.deg[z];
    SA.cnt[z] = (int*)(degcnt + (size_t)2 * NN * z + NN);
    SA.edata[z] = (int2*)alloc((size_t)NN * CAP * 8);
  }

  // ---- weight split table ----
  const float* Wsrc[10] = {Wg1, Wg2, lx1_w, lx2_w, lx3_w, Wd1, Wd2, ly1_w, ly2_w, ly3_w};
  u16* Thd[10] = {wg1h[0], wg2h[0], wl1h[0], wl2h[0], wl3h[0],
                  wg1h[1], wg2h[1], wl1h[1], wl2h[1], wl3h[1]};
  u16* Tld[10] = {wg1l[0], wg2l[0], wl1l[0], wl2l[0], wl3l[0],
                  wg1l[1], wg2l[1], wl1l[1], wl2l[1], wl3l[1]};
  int Ks[10] = {512, 512, 512, 256, 128, 512, 512, 512, 256, 128};
  int Ns[10] = {512, 512, 256, 128, 64, 512, 512, 256, 128, 64};
  int acc_t = 0;
  for (int m = 0; m < 10; ++m) {
    PF.wt.W[m] = Wsrc[m]; PF.wt.Th[m] = Thd[m]; PF.wt.Tl[m] = Tld[m];
    PF.wt.K[m] = Ks[m]; PF.wt.N[m] = Ns[m];
    PF.wt.toff[m] = acc_t;
    acc_t += (Ns[m] / 32) * (Ks[m] / 32);
  }
  PF.wt.toff[10] = acc_t;       // 1360
  int wthalf = acc_t / 2;       // 680

  int sb = (MP * FF / 4 + 255) / 256;  // 4032
  int eb = (NE + 255) / 256;           // 1000

  MMArgs MA;
  AggArgs GA;
  for (int z = 0; z < 2; ++z) {
    MA.bias[z] = nullptr; MA.C[z] = nullptr; MA.Ch[z] = nullptr; MA.Cl[z] = nullptr;
    GA.XWh[z] = xwh[z];
    GA.cnt[z] = SA.cnt[z];
    GA.deg[z] = SA.deg[z];
    GA.edata[z] = SA.edata[z];
    GA.Hh[z] = hh[z]; GA.Hl[z] = hl[z];
  }

  // ---- preprocessing: memset -> fused pre ----
  hipMemsetAsync(degcnt, 0, (size_t)4 * NN * 4, stream);
  k_pre<<<dim3(sb + eb + wthalf, 1, 2), 256, 0, stream>>>(
      PF, sb, eb, wthalf, NN * FF, MP * FF, NE, NN);

  // ---- GCN1 GEMM fused with bucket scatter ----
  for (int z = 0; z < 2; ++z) {
    MA.Ah[z] = hh[z]; MA.Al[z] = hl[z];
    MA.Bh[z] = wg1h[z]; MA.Bl[z] = wg1l[z];
    MA.Ch[z] = xwh[z];
  }
  k_g1s<<<dim3(504 + 2 * eb, 1, 1), 256, 0, stream>>>(MA, SA, NE);
  GA.bias[0] = bg1; GA.bias[1] = bd1;
  k_aggregate<<<dim3(8000, 1, 2), 256, 0, stream>>>(GA);

  // ---- GCN layer 2 ----
  for (int z = 0; z < 2; ++z) { MA.Bh[z] = wg2h[z]; MA.Bl[z] = wg2l[z]; }
  k_mm<false, false, 2, false, false><<<dim3(63, FF / 128, 2), 256, 0, stream>>>(MA, NN, FF, FF);
  GA.bias[0] = bg2; GA.bias[1] = bd2;
  k_aggregate<<<dim3(8000, 1, 2), 256, 0, stream>>>(GA);

  // ---- MLP1: 512 -> 256, hi+lo planes out ----
  MA.bias[0] = lx1_b; MA.bias[1] = ly1_b;
  for (int z = 0; z < 2; ++z) {
    MA.Bh[z] = wl1h[z]; MA.Bl[z] = wl1l[z];
    MA.Ch[z] = p1h[z]; MA.Cl[z] = p1l[z];
  }
  k_mm<true, true, 1, false, false><<<dim3(63, 2, 2), 256, 0, stream>>>(MA, NN, 256, FF);

  // ---- MLP2: 256 -> 128 ----
  MA.bias[0] = lx2_b; MA.bias[1] = ly2_b;
  for (int z = 0; z < 2; ++z) {
    MA.Ah[z] = p1h[z]; MA.Al[z] = p1l[z];
    MA.Bh[z] = wl2h[z]; MA.Bl[z] = wl2l[z];
    MA.Ch[z] = p2h[z]; MA.Cl[z] = p2l[z];
  }
  k_mm<true, true, 1, false, false><<<dim3(63, 1, 2), 256, 0, stream>>>(MA, NN, 128, 256);

  // ---- MLP3: 128 -> 64 (N-guard) ----
  MA.bias[0] = lx3_b; MA.bias[1] = ly3_b;
  for (int z = 0; z < 2; ++z) {
    MA.Ah[z] = p2h[z]; MA.Al[z] = p2l[z];
    MA.Bh[z] = wl3h[z]; MA.Bl[z] = wl3l[z];
    MA.Ch[z] = fh[z]; MA.Cl[z] = fl[z];
  }
  k_mm<true, true, 1, true, false><<<dim3(63, 1, 2), 256, 0, stream>>>(MA, NN, 64, 128);

  // ---- scores = x @ y^T (4 blocks/CU, nontemporal 256 MB write) ----
  MMArgs SC;
  SC.Ah[0] = fh[0]; SC.Al[0] = fl[0];
  SC.Bh[0] = fh[1]; SC.Bl[0] = fl[1];
  SC.Ah[1] = SC.Ah[0]; SC.Al[1] = SC.Al[0]; SC.Bh[1] = SC.Bh[0]; SC.Bl[1] = SC.Bl[0];
  SC.bias[0] = nullptr; SC.bias[1] = nullptr;
  SC.C[0] = out; SC.C[1] = out;
  SC.Ch[0] = SC.Ch[1] = nullptr; SC.Cl[0] = SC.Cl[1] = nullptr;
  k_score<<<dim3(63, 63, 1), 256, 0, stream>>>(SC, NN, NN, 64);
}

// Round 19
// 334.821 us; speedup vs baseline: 1.3987x; 1.0097x over previous
//
#include <hip/hip_runtime.h>

typedef unsigned short u16;
typedef unsigned int u32;
typedef __attribute__((ext_vector_type(8))) short bf16x8;
typedef __attribute__((ext_vector_type(4))) float f32x4;
typedef __attribute__((ext_vector_type(4))) unsigned short u16x4;
typedef __attribute__((ext_vector_type(2))) unsigned short u16x2;

static const int NN = 8000;    // nodes per graph (M == D)
static const int NE = 256000;  // edges per graph
static const int FF = 512;     // feature dim
static const int MP = 8064;    // 63 * 128 padded rows
static const int CAP = 128;    // edge bucket capacity (deg: mean 32, sd 5.7)

__device__ __forceinline__ u16 f2bf(float x) {
  union { float f; u32 u; } a; a.f = x;
  u32 r = a.u + 0x7FFF + ((a.u >> 16) & 1);  // RNE
  return (u16)(r >> 16);
}
__device__ __forceinline__ float bf2f(u16 b) {
  union { float f; u32 u; } a; a.u = ((u32)b) << 16;
  return a.f;
}

__device__ __forceinline__ void gload_lds16(const void* g, void* l) {
  __builtin_amdgcn_global_load_lds(
      (const __attribute__((address_space(1))) unsigned int*)g,
      (__attribute__((address_space(3))) unsigned int*)l, 16, 0, 0);
}

// ---------------- arg structs (blockIdx.z = graph where applicable) --------

struct WTAll {
  const float* W[10];
  u16* Th[10];
  u16* Tl[10];
  int K[10], N[10];
  int toff[11];
};

// fused preprocessing: act-split | edge-weight gather | weight splits
struct PreFused {
  const float* x[2];
  u16* ph[2];
  u16* pl[2];
  const float* data[2];
  const int* ei[2];
  float* wbuf[2];
  float* deg[2];   // zeroed by memset; accumulates sum(w)
  WTAll wt;
};

struct ScatArgs {
  const int* ei[2];
  const float* wbuf[2];
  const float* deg[2];
  int* cnt[2];     // zeroed by memset; bucket fill counts
  int2* edata[2];  // bucketed [node][CAP]: (src byte-offset, norm-bits)
};

struct MMArgs {
  const u16* Ah[2]; const u16* Al[2];
  const u16* Bh[2]; const u16* Bl[2];
  const float* bias[2];
  float* C[2];             // fp32 output (OUTMODE 0)
  u16* Ch[2]; u16* Cl[2];  // plane outputs (OUTMODE 1 = hi+lo, 2 = hi only)
};

struct AggArgs {
  const u16* XWh[2];       // bf16-hi XW planes [MP][FF]
  const int* cnt[2];
  const float* deg[2];
  const int2* edata[2];
  const float* bias[2];
  u16* Hh[2];
  u16* Hl[2];
};

// ---------------- fused preprocessing ----------------
// block ranges: [0,sb) act-split | [sb,sb+eb) edge weights | rest: W splits.

__global__ __launch_bounds__(256) void k_pre(PreFused a, int sb, int eb, int wthalf,
                                             int tot_in, int tot_pad, int E, int n) {
  int z = blockIdx.z;
  int b = blockIdx.x;
  int tid = threadIdx.x;
  if (b < sb) {
    int i = (b * 256 + tid) * 4;
    if (i >= tot_pad) return;
    float4 v = (i < tot_in) ? *(const float4*)&a.x[z][i] : make_float4(0.f, 0.f, 0.f, 0.f);
    u16x4 h, l;
#pragma unroll
    for (int e = 0; e < 4; ++e) {
      float x = (&v.x)[e];
      u16 hh = f2bf(x);
      h[e] = hh;
      l[e] = f2bf(x - bf2f(hh));
    }
    *(u16x4*)&a.ph[z][i] = h;
    *(u16x4*)&a.pl[z][i] = l;
  } else if (b < sb + eb) {
    int e = (b - sb) * 256 + tid;
    if (e >= E) return;
    const int* ei = a.ei[z];
    int r = ei[e];
    int c = ei[E + e];
    float w = fmaxf(a.data[z][(size_t)r * n + c], 0.0f);
    a.wbuf[z][e] = w;
    atomicAdd(&a.deg[z][c], w);
  } else {
    int bid = (b - sb - eb) + z * wthalf;
    int m = 0;
    while (bid >= a.wt.toff[m + 1]) ++m;
    int local = bid - a.wt.toff[m];
    int K = a.wt.K[m], N = a.wt.N[m];
    int ntn = N >> 5;
    int n0 = (local % ntn) * 32, k0 = (local / ntn) * 32;
    const float* W = a.wt.W[m];
    u16* Th = a.wt.Th[m];
    u16* Tl = a.wt.Tl[m];
    __shared__ float tile[32][33];
    int tx = tid & 31, ty = tid >> 5;
#pragma unroll
    for (int r = 0; r < 32; r += 8)
      tile[r + ty][tx] = W[(size_t)(k0 + r + ty) * N + n0 + tx];
    __syncthreads();
#pragma unroll
    for (int r = 0; r < 32; r += 8) {
      float v = tile[tx][r + ty];
      int nn = n0 + r + ty, k = k0 + tx;
      u16 h = f2bf(v);
      Th[(size_t)nn * K + k] = h;
      Tl[(size_t)nn * K + k] = f2bf(v - bf2f(h));
    }
  }
}

// ---------------- bf16x3 MFMA GEMM body ----------------
// OUTMODE: 0 = fp32 C, 1 = bf16 hi+lo planes, 2 = bf16 hi-only plane.

template <bool BIAS, bool RELU, int OUTMODE, bool GUARD, bool NT>
__device__ __forceinline__ void mm_body(char* smem, const MMArgs& a,
                                        int M, int N, int K,
                                        int bx, int by, int z) {
  u16 (*lds)[4][4096] = (u16(*)[4][4096])smem;
  float* ct = (float*)smem;

  int tid = threadIdx.x;
  int wv = tid >> 6, ln = tid & 63;
  int l15 = ln & 15, l4 = ln >> 4;
  int m0 = bx * 128, n0 = by * 128;
  int wm = (wv & 1) * 64, wn = (wv >> 1) * 64;
  const u16* gb = (wv == 0) ? a.Ah[z] : (wv == 1) ? a.Al[z] : (wv == 2) ? a.Bh[z] : a.Bl[z];
  int row0 = (wv < 2) ? m0 : n0;

  f32x4 acc[4][4];
  f32x4 zz = {0.f, 0.f, 0.f, 0.f};
#pragma unroll
  for (int i = 0; i < 4; ++i)
#pragma unroll
    for (int j = 0; j < 4; ++j) acc[i][j] = zz;

  auto stage = [&](int d, int k0) {
#pragma unroll
    for (int it = 0; it < 8; ++it) {
      int slot = it * 64 + ln;
      int r = slot >> 2, c = slot & 3;
      int gc = c ^ ((r >> 2) & 3);
      gload_lds16(gb + ((size_t)(row0 + r) * K + k0 + gc * 8),
                  &lds[d][wv][it * 512]);
    }
  };

  auto compute = [&](int d) {
    bf16x8 ah[4], al[4], bh[4], bl[4];
#pragma unroll
    for (int i = 0; i < 4; ++i) {
      int r = wm + i * 16 + l15;
      int off = r * 32 + ((l4 ^ ((r >> 2) & 3)) << 3);
      ah[i] = *(const bf16x8*)&lds[d][0][off];
      al[i] = *(const bf16x8*)&lds[d][1][off];
    }
#pragma unroll
    for (int j = 0; j < 4; ++j) {
      int r = wn + j * 16 + l15;
      int off = r * 32 + ((l4 ^ ((r >> 2) & 3)) << 3);
      bh[j] = *(const bf16x8*)&lds[d][2][off];
      bl[j] = *(const bf16x8*)&lds[d][3][off];
    }
#pragma unroll
    for (int i = 0; i < 4; ++i)
#pragma unroll
      for (int j = 0; j < 4; ++j) {
        acc[i][j] = __builtin_amdgcn_mfma_f32_16x16x32_bf16(ah[i], bh[j], acc[i][j], 0, 0, 0);
        acc[i][j] = __builtin_amdgcn_mfma_f32_16x16x32_bf16(al[i], bh[j], acc[i][j], 0, 0, 0);
        acc[i][j] = __builtin_amdgcn_mfma_f32_16x16x32_bf16(ah[i], bl[j], acc[i][j], 0, 0, 0);
      }
  };

  stage(0, 0);
  __syncthreads();
  int nk = K >> 5;
  for (int t = 0; t < nk; ++t) {
    int cur = t & 1;
    if (t + 1 < nk) stage(cur ^ 1, (t + 1) << 5);
    compute(cur);
    __syncthreads();
  }

  // ---- epilogue: acc (D layout col=lane&15, row=4*(lane>>4)+reg) -> LDS ----
#pragma unroll
  for (int i = 0; i < 4; ++i)
#pragma unroll
    for (int rr = 0; rr < 4; ++rr) {
      int row = wm + i * 16 + l4 * 4 + rr;
#pragma unroll
      for (int j = 0; j < 4; ++j) {
        int col = wn + l15 + j * 16;
        ct[row * 132 + col] = acc[i][j][rr];
      }
    }
  __syncthreads();

  int tcol = (tid & 31) * 4;
  int trow = tid >> 5;
#pragma unroll
  for (int p = 0; p < 16; ++p) {
    int row = p * 8 + trow;
    int m = m0 + row;
    int n = n0 + tcol;
    if (GUARD && n >= N) continue;
    f32x4 v = *(f32x4*)&ct[row * 132 + tcol];
    float o[4];
#pragma unroll
    for (int e = 0; e < 4; ++e) {
      float x = v[e];
      if (BIAS) x += a.bias[z][n + e];
      if (RELU) x = fmaxf(x, 0.0f);
      o[e] = x;
    }
    if (OUTMODE >= 1) {
      u16x4 hh, ll;
      if (m < M) {
#pragma unroll
        for (int e = 0; e < 4; ++e) {
          u16 h = f2bf(o[e]);
          hh[e] = h;
          if (OUTMODE == 1) ll[e] = f2bf(o[e] - bf2f(h));
        }
      } else {
#pragma unroll
        for (int e = 0; e < 4; ++e) { hh[e] = 0; ll[e] = 0; }
      }
      *(u16x4*)&a.Ch[z][(size_t)m * N + n] = hh;
      if (OUTMODE == 1) *(u16x4*)&a.Cl[z][(size_t)m * N + n] = ll;
    } else {
      if (m < M) {
        f32x4 o4 = {o[0], o[1], o[2], o[3]};
        if (NT)
          __builtin_nontemporal_store(o4, (f32x4*)&a.C[z][(size_t)m * N + n]);
        else
          *(f32x4*)&a.C[z][(size_t)m * N + n] = o4;
      }
    }
  }
}

template <bool BIAS, bool RELU, int OUTMODE, bool GUARD, bool NT>
__global__ __launch_bounds__(256) void k_mm(MMArgs a, int M, int N, int K) {
  __shared__ __align__(16) char smem[67584];
  mm_body<BIAS, RELU, OUTMODE, GUARD, NT>(smem, a, M, N, K,
                                          blockIdx.x, blockIdx.y, blockIdx.z);
}

// ---------------- fused GCN1 GEMM + bucket scatter ----------------

__global__ __launch_bounds__(256) void k_g1s(MMArgs ma, ScatArgs sa, int E) {
  __shared__ __align__(16) char smem[67584];
  int f = blockIdx.x;
  if (f < 504) {
    int z = f / 252, rem = f % 252;
    mm_body<false, false, 2, false, false>(smem, ma, NN, FF, FF,
                                           rem % 63, rem / 63, z);
  } else {
    int s = f - 504;
    int z = s >= 1000 ? 1 : 0;
    int e = (s - z * 1000) * 256 + threadIdx.x;
    if (e >= E) return;
    const int* ei = sa.ei[z];
    int r = ei[e], c = ei[E + e];
    float w = sa.wbuf[z][e];
    float dr = 1.0f / sqrtf(1.0f + sa.deg[z][r]);
    float dc = 1.0f / sqrtf(1.0f + sa.deg[z][c]);
    int slot = atomicAdd(&sa.cnt[z][c], 1);
    int2 sn;
    sn.x = r << 10;  // pre-scaled byte offset: r * FF * 2
    sn.y = __float_as_int(dr * w * dc);
    sa.edata[z][(size_t)c * CAP + slot] = sn;
  }
}

// ---------------- score GEMM: 128x128 tile, K=64, 4 blocks/CU -------------
// Single-buffered staging (32KB) + half-tile epilogue (64x132 f32 = 33KB,
// overlays staging) -> 33.8KB LDS; launch_bounds(256,4) caps VGPR at 128
// (b-fragments loaded per-j). Write-bound: 2x blocks in flight vs k_mm.

__global__ __launch_bounds__(256, 4) void k_score(MMArgs a, int M, int N, int K) {
  __shared__ __align__(16) char smem[33792];
  u16 (*lds)[4096] = (u16(*)[4096])smem;  // [plane][128*32]
  float* ct = (float*)smem;               // 64 x 132 half tile

  int tid = threadIdx.x;
  int wv = tid >> 6, ln = tid & 63;
  int l15 = ln & 15, l4 = ln >> 4;
  int m0 = blockIdx.x * 128, n0 = blockIdx.y * 128;
  int wm = (wv & 1) * 64, wn = (wv >> 1) * 64;
  const u16* gb = (wv == 0) ? a.Ah[0] : (wv == 1) ? a.Al[0] : (wv == 2) ? a.Bh[0] : a.Bl[0];
  int row0 = (wv < 2) ? m0 : n0;

  f32x4 acc[4][4];
  f32x4 zz = {0.f, 0.f, 0.f, 0.f};
#pragma unroll
  for (int i = 0; i < 4; ++i)
#pragma unroll
    for (int j = 0; j < 4; ++j) acc[i][j] = zz;

  int nk = K >> 5;
  for (int t = 0; t < nk; ++t) {
    int k0 = t << 5;
#pragma unroll
    for (int it = 0; it < 8; ++it) {
      int slot = it * 64 + ln;
      int r = slot >> 2, c = slot & 3;
      int gc = c ^ ((r >> 2) & 3);
      gload_lds16(gb + ((size_t)(row0 + r) * K + k0 + gc * 8),
                  &lds[wv][it * 512]);
    }
    __syncthreads();
    bf16x8 ah[4], al[4];
#pragma unroll
    for (int i = 0; i < 4; ++i) {
      int r = wm + i * 16 + l15;
      int off = r * 32 + ((l4 ^ ((r >> 2) & 3)) << 3);
      ah[i] = *(const bf16x8*)&lds[0][off];
      al[i] = *(const bf16x8*)&lds[1][off];
    }
#pragma unroll
    for (int j = 0; j < 4; ++j) {
      int r = wn + j * 16 + l15;
      int off = r * 32 + ((l4 ^ ((r >> 2) & 3)) << 3);
      bf16x8 bh = *(const bf16x8*)&lds[2][off];
      bf16x8 bl = *(const bf16x8*)&lds[3][off];
#pragma unroll
      for (int i = 0; i < 4; ++i) {
        acc[i][j] = __builtin_amdgcn_mfma_f32_16x16x32_bf16(ah[i], bh, acc[i][j], 0, 0, 0);
        acc[i][j] = __builtin_amdgcn_mfma_f32_16x16x32_bf16(al[i], bh, acc[i][j], 0, 0, 0);
        acc[i][j] = __builtin_amdgcn_mfma_f32_16x16x32_bf16(ah[i], bl, acc[i][j], 0, 0, 0);
      }
    }
    __syncthreads();
  }

  int tcol = (tid & 31) * 4;
  int trow = tid >> 5;
#pragma unroll
  for (int h = 0; h < 2; ++h) {
    if ((wv & 1) == h) {
#pragma unroll
      for (int i = 0; i < 4; ++i)
#pragma unroll
        for (int rr = 0; rr < 4; ++rr) {
          int row = i * 16 + l4 * 4 + rr;
#pragma unroll
          for (int j = 0; j < 4; ++j)
            ct[row * 132 + wn + l15 + j * 16] = acc[i][j][rr];
        }
    }
    __syncthreads();
#pragma unroll
    for (int p = 0; p < 8; ++p) {
      int row = p * 8 + trow;
      int m = m0 + h * 64 + row;
      int n = n0 + tcol;
      if (n < N && m < M) {
        f32x4 v = *(f32x4*)&ct[row * 132 + tcol];
        __builtin_nontemporal_store(v, (f32x4*)&a.C[0][(size_t)m * N + n]);
      }
    }
    __syncthreads();
  }
}

// ---------------- sparse aggregation: half-wave u16x4 gathers --------------
// Lanes 0-31 process even edges, 32-63 odd edges; each lane gathers u16x4
// (4 elems, 8B) so one instruction covers an edge's 128-elem chunk per half.
// Halves merged at the end via one shfl_xor(32) per elem. Chunk slab = 2MB
// (chunk = bid&3, L2-resident both graphs). LDS edge staging; 4 independent
// accumulator banks; no atomics; static single-writer (G16-safe).

__global__ __launch_bounds__(256) void k_aggregate(AggArgs a) {
  __shared__ int2 ebuf[4][64];
  int z = blockIdx.z;
  int bid = blockIdx.x;               // 0..7999
  int wv = threadIdx.x >> 6, ln = threadIdx.x & 63;
  int half = ln >> 5, li = ln & 31;
  int chunk = bid & 3;                // 4 chunks x 128 elems (2MB slab)
  int c = (bid >> 2) * 4 + wv;        // node 0..7999
  int fo = chunk * 128 + li * 4;      // 4 elems/lane over 32 lanes
  const char* XWb = (const char*)a.XWh[z];
  size_t fo2 = (size_t)fo * 2;        // byte offset within row
  const int2* ed = a.edata[z] + (size_t)c * CAP;
  int cn = a.cnt[z][c];
  float di = 1.0f / sqrtf(1.0f + a.deg[z][c]);
  float sl = di * di;

  float acc4[4][4];                   // [bank][elem]
#pragma unroll
  for (int q = 0; q < 4; ++q)
#pragma unroll
    for (int e = 0; e < 4; ++e) acc4[q][e] = 0.f;

  for (int base = 0; base < cn; base += 64) {
    if (base + ln < cn) ebuf[wv][ln] = ed[base + ln];
    int rem = cn - base;
    int ne = rem < 64 ? rem : 64;
    int jj = 0;
    for (; jj + 8 <= ne; jj += 8) {   // 8 edges: 4 per half
      int2 d[4];
#pragma unroll
      for (int q = 0; q < 4; ++q) d[q] = ebuf[wv][jj + 2 * q + half];
      u16x4 qv[4];
#pragma unroll
      for (int q = 0; q < 4; ++q)
        qv[q] = *(const u16x4*)(XWb + (size_t)(u32)d[q].x + fo2);
#pragma unroll
      for (int q = 0; q < 4; ++q) {
        float w = __int_as_float(d[q].y);
#pragma unroll
        for (int e = 0; e < 4; ++e)
          acc4[q][e] = fmaf(w, bf2f(qv[q][e]), acc4[q][e]);
      }
    }
    for (int j = jj + half; j < ne; j += 2) {
      int2 d0 = ebuf[wv][j];
      u16x4 q0 = *(const u16x4*)(XWb + (size_t)(u32)d0.x + fo2);
      float w0 = __int_as_float(d0.y);
#pragma unroll
      for (int e = 0; e < 4; ++e)
        acc4[0][e] = fmaf(w0, bf2f(q0[e]), acc4[0][e]);
    }
  }

  float s[4];
#pragma unroll
  for (int e = 0; e < 4; ++e) {
    float v = (acc4[0][e] + acc4[1][e]) + (acc4[2][e] + acc4[3][e]);
    s[e] = v + __shfl_xor(v, 32);
  }

  if (half == 0) {
    u16x4 sh = *(const u16x4*)(XWb + (size_t)c * 1024 + fo2);
    f32x4 b4 = *(const f32x4*)&a.bias[z][fo];
    u16x4 hh, ll;
#pragma unroll
    for (int e = 0; e < 4; ++e) {
      float o = fmaxf(s[e] + sl * bf2f(sh[e]) + b4[e], 0.0f);
      u16 h = f2bf(o);
      hh[e] = h;
      ll[e] = f2bf(o - bf2f(h));
    }
    *(u16x4*)&a.Hh[z][(size_t)c * FF + fo] = hh;
    *(u16x4*)&a.Hl[z][(size_t)c * FF + fo] = ll;
  }
}

// ---------------- host orchestration ----------------

extern "C" void kernel_launch(void* const* d_in, const int* in_sizes, int n_in,
                              void* d_out, int out_size, void* d_ws, size_t ws_size,
                              hipStream_t stream) {
  const float* x_m    = (const float*)d_in[0];
  const float* x_d    = (const float*)d_in[1];
  const float* data_m = (const float*)d_in[2];
  const float* data_d = (const float*)d_in[3];
  const int*   ei_m   = (const int*)d_in[4];
  const int*   ei_d   = (const int*)d_in[5];
  const float* Wg1 = (const float*)d_in[6];
  const float* bg1 = (const float*)d_in[7];
  const float* Wg2 = (const float*)d_in[8];
  const float* bg2 = (const float*)d_in[9];
  const float* Wd1 = (const float*)d_in[10];
  const float* bd1 = (const float*)d_in[11];
  const float* Wd2 = (const float*)d_in[12];
  const float* bd2 = (const float*)d_in[13];
  const float* lx1_w = (const float*)d_in[14];
  const float* lx1_b = (const float*)d_in[15];
  const float* lx2_w = (const float*)d_in[16];
  const float* lx2_b = (const float*)d_in[17];
  const float* lx3_w = (const float*)d_in[18];
  const float* lx3_b = (const float*)d_in[19];
  const float* ly1_w = (const float*)d_in[20];
  const float* ly1_b = (const float*)d_in[21];
  const float* ly2_w = (const float*)d_in[22];
  const float* ly2_b = (const float*)d_in[23];
  const float* ly3_w = (const float*)d_in[24];
  const float* ly3_b = (const float*)d_in[25];
  float* out = (float*)d_out;

  char* base = (char*)d_ws;
  size_t off = 0;
  auto alloc = [&](size_t bytes) -> char* {
    char* p = base + off;
    off += (bytes + 255) & ~(size_t)255;
    return p;
  };
  u16* hh[2], *hl[2];
  for (int z = 0; z < 2; ++z) {
    hh[z] = (u16*)alloc((size_t)MP * FF * 2);
    hl[z] = (u16*)alloc((size_t)MP * FF * 2);
  }
  u16* xwh[2];  // bf16-hi XW (GCN GEMM output / aggregation input)
  for (int z = 0; z < 2; ++z) xwh[z] = (u16*)alloc((size_t)MP * FF * 2);
  u16* p1h[2], *p1l[2], *p2h[2], *p2l[2], *fh[2], *fl[2];
  for (int z = 0; z < 2; ++z) {
    p1h[z] = (u16*)alloc((size_t)MP * 256 * 2);
    p1l[z] = (u16*)alloc((size_t)MP * 256 * 2);
    p2h[z] = (u16*)alloc((size_t)MP * 128 * 2);
    p2l[z] = (u16*)alloc((size_t)MP * 128 * 2);
    fh[z]  = (u16*)alloc((size_t)MP * 64 * 2);
    fl[z]  = (u16*)alloc((size_t)MP * 64 * 2);
  }
  u16 *wg1h[2], *wg1l[2], *wg2h[2], *wg2l[2], *wl1h[2], *wl1l[2],
      *wl2h[2], *wl2l[2], *wl3h[2], *wl3l[2];
  for (int z = 0; z < 2; ++z) {
    wg1h[z] = (u16*)alloc((size_t)512 * 512 * 2);
    wg1l[z] = (u16*)alloc((size_t)512 * 512 * 2);
    wg2h[z] = (u16*)alloc((size_t)512 * 512 * 2);
    wg2l[z] = (u16*)alloc((size_t)512 * 512 * 2);
    wl1h[z] = (u16*)alloc((size_t)512 * 256 * 2);
    wl1l[z] = (u16*)alloc((size_t)512 * 256 * 2);
    wl2h[z] = (u16*)alloc((size_t)256 * 128 * 2);
    wl2l[z] = (u16*)alloc((size_t)256 * 128 * 2);
    wl3h[z] = (u16*)alloc((size_t)128 * 64 * 2);
    wl3l[z] = (u16*)alloc((size_t)128 * 64 * 2);
  }
  // deg/cnt contiguous for one memset: [deg0|cnt0|deg1|cnt1]
  float* degcnt = (float*)alloc((size_t)4 * NN * 4);
  PreFused PF;
  ScatArgs SA;
  PF.x[0] = x_m; PF.x[1] = x_d;
  PF.data[0] = data_m; PF.data[1] = data_d;
  for (int z = 0; z < 2; ++z) {
    PF.ph[z] = hh[z]; PF.pl[z] = hl[z];
    PF.ei[z] = z ? ei_d : ei_m;
    PF.wbuf[z] = (float*)alloc((size_t)NE * 4);
    PF.deg[z] = degcnt + (size_t)2 * NN * z;
    SA.ei[z] = PF.ei[z];
    SA.wbuf[z] = PF.wbuf[z];
    SA.deg[z] = PF.deg[z];
    SA.cnt[z] = (int*)(degcnt + (size_t)2 * NN * z + NN);
    SA.edata[z] = (int2*)alloc((size_t)NN * CAP * 8);
  }

  // ---- weight split table ----
  const float* Wsrc[10] = {Wg1, Wg2, lx1_w, lx2_w, lx3_w, Wd1, Wd2, ly1_w, ly2_w, ly3_w};
  u16* Thd[10] = {wg1h[0], wg2h[0], wl1h[0], wl2h[0], wl3h[0],
                  wg1h[1], wg2h[1], wl1h[1], wl2h[1], wl3h[1]};
  u16* Tld[10] = {wg1l[0], wg2l[0], wl1l[0], wl2l[0], wl3l[0],
                  wg1l[1], wg2l[1], wl1l[1], wl2l[1], wl3l[1]};
  int Ks[10] = {512, 512, 512, 256, 128, 512, 512, 512, 256, 128};
  int Ns[10] = {512, 512, 256, 128, 64, 512, 512, 256, 128, 64};
  int acc_t = 0;
  for (int m = 0; m < 10; ++m) {
    PF.wt.W[m] = Wsrc[m]; PF.wt.Th[m] = Thd[m]; PF.wt.Tl[m] = Tld[m];
    PF.wt.K[m] = Ks[m]; PF.wt.N[m] = Ns[m];
    PF.wt.toff[m] = acc_t;
    acc_t += (Ns[m] / 32) * (Ks[m] / 32);
  }
  PF.wt.toff[10] = acc_t;       // 1360
  int wthalf = acc_t / 2;       // 680

  int sb = (MP * FF / 4 + 255) / 256;  // 4032
  int eb = (NE + 255) / 256;           // 1000

  MMArgs MA;
  AggArgs GA;
  for (int z = 0; z < 2; ++z) {
    MA.bias[z] = nullptr; MA.C[z] = nullptr; MA.Ch[z] = nullptr; MA.Cl[z] = nullptr;
    GA.XWh[z] = xwh[z];
    GA.cnt[z] = SA.cnt[z];
    GA.deg[z] = SA.deg[z];
    GA.edata[z] = SA.edata[z];
    GA.Hh[z] = hh[z]; GA.Hl[z] = hl[z];
  }

  // ---- preprocessing: memset -> fused pre ----
  hipMemsetAsync(degcnt, 0, (size_t)4 * NN * 4, stream);
  k_pre<<<dim3(sb + eb + wthalf, 1, 2), 256, 0, stream>>>(
      PF, sb, eb, wthalf, NN * FF, MP * FF, NE, NN);

  // ---- GCN1 GEMM fused with bucket scatter ----
  for (int z = 0; z < 2; ++z) {
    MA.Ah[z] = hh[z]; MA.Al[z] = hl[z];
    MA.Bh[z] = wg1h[z]; MA.Bl[z] = wg1l[z];
    MA.Ch[z] = xwh[z];
  }
  k_g1s<<<dim3(504 + 2 * eb, 1, 1), 256, 0, stream>>>(MA, SA, NE);
  GA.bias[0] = bg1; GA.bias[1] = bd1;
  k_aggregate<<<dim3(8000, 1, 2), 256, 0, stream>>>(GA);

  // ---- GCN layer 2 ----
  for (int z = 0; z < 2; ++z) { MA.Bh[z] = wg2h[z]; MA.Bl[z] = wg2l[z]; }
  k_mm<false, false, 2, false, false><<<dim3(63, FF / 128, 2), 256, 0, stream>>>(MA, NN, FF, FF);
  GA.bias[0] = bg2; GA.bias[1] = bd2;
  k_aggregate<<<dim3(8000, 1, 2), 256, 0, stream>>>(GA);

  // ---- MLP1: 512 -> 256, hi+lo planes out ----
  MA.bias[0] = lx1_b; MA.bias[1] = ly1_b;
  for (int z = 0; z < 2; ++z) {
    MA.Bh[z] = wl1h[z]; MA.Bl[z] = wl1l[z];
    MA.Ch[z] = p1h[z]; MA.Cl[z] = p1l[z];
  }
  k_mm<true, true, 1, false, false><<<dim3(63, 2, 2), 256, 0, stream>>>(MA, NN, 256, FF);

  // ---- MLP2: 256 -> 128 ----
  MA.bias[0] = lx2_b; MA.bias[1] = ly2_b;
  for (int z = 0; z < 2; ++z) {
    MA.Ah[z] = p1h[z]; MA.Al[z] = p1l[z];
    MA.Bh[z] = wl2h[z]; MA.Bl[z] = wl2l[z];
    MA.Ch[z] = p2h[z]; MA.Cl[z] = p2l[z];
  }
  k_mm<true, true, 1, false, false><<<dim3(63, 1, 2), 256, 0, stream>>>(MA, NN, 128, 256);

  // ---- MLP3: 128 -> 64 (N-guard) ----
  MA.bias[0] = lx3_b; MA.bias[1] = ly3_b;
  for (int z = 0; z < 2; ++z) {
    MA.Ah[z] = p2h[z]; MA.Al[z] = p2l[z];
    MA.Bh[z] = wl3h[z]; MA.Bl[z] = wl3l[z];
    MA.Ch[z] = fh[z]; MA.Cl[z] = fl[z];
  }
  k_mm<true, true, 1, true, false><<<dim3(63, 1, 2), 256, 0, stream>>>(MA, NN, 64, 128);

  // ---- scores = x @ y^T (4 blocks/CU, nontemporal 256 MB write) ----
  MMArgs SC;
  SC.Ah[0] = fh[0]; SC.Al[0] = fl[0];
  SC.Bh[0] = fh[1]; SC.Bl[0] = fl[1];
  SC.Ah[1] = SC.Ah[0]; SC.Al[1] = SC.Al[0]; SC.Bh[1] = SC.Bh[0]; SC.Bl[1] = SC.Bl[0];
  SC.bias[0] = nullptr; SC.bias[1] = nullptr;
  SC.C[0] = out; SC.C[1] = out;
  SC.Ch[0] = SC.Ch[1] = nullptr; SC.Cl[0] = SC.Cl[1] = nullptr;
  k_score<<<dim3(63, 63, 1), 256, 0, stream>>>(SC, NN, NN, 64);
}